// Round 6
// baseline (297.430 us; speedup 1.0000x reference)
//
#include <hip/hip_runtime.h>

#define EXPC 0.25505654442163f  // (1/sqrt(32)) * log2(e)

typedef __attribute__((ext_vector_type(8))) short bfrag;   // 8 bf16
typedef __attribute__((ext_vector_type(4))) float ffrag;   // 4 f32 acc
typedef __attribute__((ext_vector_type(8))) unsigned int u8v;
typedef __attribute__((ext_vector_type(4))) unsigned int u4v;
typedef __attribute__((ext_vector_type(2))) unsigned int u2v;

__device__ __forceinline__ short f2bf(float x) {
  union { float f; unsigned u; } v; v.f = x;
  return (short)((v.u + 0x8000u) >> 16);  // round-half-up
}

__device__ __forceinline__ unsigned int packbf(float a, float b) {
  return __builtin_amdgcn_perm(__float_as_uint(b) + 0x8000u,
                               __float_as_uint(a) + 0x8000u, 0x07060302u);
}

__device__ __forceinline__ bfrag cvtp(u8v x) {
  u4v r;
#pragma unroll
  for (int i = 0; i < 4; ++i)
    r[i] = __builtin_amdgcn_perm(x[2 * i + 1] + 0x8000u, x[2 * i] + 0x8000u, 0x07060302u);
  union { u4v u; bfrag b; } c; c.u = r; return c.b;
}
__device__ __forceinline__ bfrag cvt8(const float* __restrict__ p) {
  return cvtp(*(const u8v*)p);
}

// ---- fused K+V projection, LDS-staged (coalesced 128B-line loads) ----
// blocks 0..255:  K: C[64 kin-rows][256 d] -> ko[16384][256]
// blocks 256..511: V: C[256 d][64 vin-rows] -> vt[bt][256][1024] (transposed)
__global__ __launch_bounds__(256, 3) void proj_kv(
    const float* __restrict__ kin, const float* __restrict__ Wk,
    const float* __restrict__ bk, const float* __restrict__ vin,
    const float* __restrict__ Wv, const float* __restrict__ bv,
    short* __restrict__ ko, short* __restrict__ vt) {
  const int t = threadIdx.x;
  const int lane = t & 63, wid = t >> 6;      // 4 waves
  const int lrow = lane & 15, lq = lane >> 4;
  __shared__ __align__(16) char lds[40960];
  short* Ab = (short*)lds;              // [<=256][40] bf16, 80B rows (16B-aligned)
  short* Bb = (short*)(lds + 20480);    // [<=256][40]
  short* tile = (short*)lds;            // epilogue reuse

  const bool isK = blockIdx.x < 256;
  const int bx = isK ? blockIdx.x : blockIdx.x - 256;
  const int m0 = bx * 64;               // K: kin row base; V: vin row base (n0)
  const int row4 = t >> 2, c4 = (t & 3) * 8;

  ffrag acc[4][4] = {};
#pragma unroll 1
  for (int s = 0; s < 8; ++s) {
    const int k0 = s * 32;
    if (s) __syncthreads();
    // ---- stage slab: 4 lanes x 32B consecutive per row (full 128B lines) ----
    if (isK) {
      *(bfrag*)(Ab + row4 * 40 + c4) =
          cvt8(kin + (size_t)(m0 + row4) * 256 + k0 + c4);
#pragma unroll
      for (int seg = 0; seg < 4; ++seg)
        *(bfrag*)(Bb + (seg * 64 + row4) * 40 + c4) =
            cvt8(Wk + (size_t)(seg * 64 + row4) * 256 + k0 + c4);
    } else {
      *(bfrag*)(Bb + row4 * 40 + c4) =
          cvt8(vin + (size_t)(m0 + row4) * 256 + k0 + c4);
#pragma unroll
      for (int seg = 0; seg < 4; ++seg)
        *(bfrag*)(Ab + (seg * 64 + row4) * 40 + c4) =
            cvt8(Wv + (size_t)(seg * 64 + row4) * 256 + k0 + c4);
    }
    __syncthreads();
    // ---- fragments from LDS + MFMA ----
    bfrag a[4], b[4];
    if (isK) {
#pragma unroll
      for (int i = 0; i < 4; ++i)
        a[i] = *(const bfrag*)(Ab + (i * 16 + lrow) * 40 + lq * 8);
#pragma unroll
      for (int j = 0; j < 4; ++j)
        b[j] = *(const bfrag*)(Bb + (wid * 64 + j * 16 + lrow) * 40 + lq * 8);
    } else {
#pragma unroll
      for (int i = 0; i < 4; ++i)
        a[i] = *(const bfrag*)(Ab + (wid * 64 + i * 16 + lrow) * 40 + lq * 8);
#pragma unroll
      for (int j = 0; j < 4; ++j)
        b[j] = *(const bfrag*)(Bb + (j * 16 + lrow) * 40 + lq * 8);
    }
#pragma unroll
    for (int i = 0; i < 4; ++i)
#pragma unroll
      for (int j = 0; j < 4; ++j)
        acc[i][j] = __builtin_amdgcn_mfma_f32_16x16x32_bf16(a[i], b[j], acc[i][j], 0, 0, 0);
  }
  __syncthreads();

  if (isK) {
    // C[m = i*16+lq*4+r][d = wid*64+j*16+lrow]; tile [64][264] (528B rows)
#pragma unroll
    for (int j = 0; j < 4; ++j) {
      int d = wid * 64 + j * 16 + lrow;
      float bs = bk[d];
#pragma unroll
      for (int i = 0; i < 4; ++i)
#pragma unroll
        for (int r = 0; r < 4; ++r)
          tile[(i * 16 + lq * 4 + r) * 264 + d] = f2bf(acc[i][j][r] + bs);
    }
    __syncthreads();
#pragma unroll
    for (int p = 0; p < 8; ++p) {
      int row = p * 8 + (t >> 5), c = t & 31;
      bfrag v = *(const bfrag*)(tile + row * 264 + c * 8);
      *(bfrag*)(ko + (size_t)(m0 + row) * 256 + c * 8) = v;
    }
  } else {
    // C[d = wid*64+i*16+lq*4+r][srow = j*16+lrow]; tile [256][72] (144B rows)
#pragma unroll
    for (int i = 0; i < 4; ++i)
#pragma unroll
      for (int r = 0; r < 4; ++r) {
        int d = wid * 64 + i * 16 + lq * 4 + r;
        float bs = bv[d];
#pragma unroll
        for (int j = 0; j < 4; ++j)
          tile[d * 72 + j * 16 + lrow] = f2bf(acc[i][j][r] + bs);
      }
    __syncthreads();
    const int bt = m0 >> 10, sl0 = m0 & 1023;
#pragma unroll
    for (int p = 0; p < 8; ++p) {
      int d = p * 32 + (t >> 3), c = t & 7;
      bfrag v = *(const bfrag*)(tile + d * 72 + c * 8);
      *(bfrag*)(vt + (size_t)bt * 262144 + (size_t)d * 1024 + sl0 + c * 8) = v;
    }
  }
}

// ---- fused: Q-proj -> attention (S^T, dual chunk-stream) -> out-proj ----
// grid 1024 x 512 thr; 16 q-rows/block; wave = 1 head, 2 independent chunk streams.
__global__ __launch_bounds__(512, 4) void attn_fused(
    const float* __restrict__ query, const float* __restrict__ Wq,
    const float* __restrict__ bq, const float* __restrict__ Wo,
    const float* __restrict__ bo, const short* __restrict__ K,
    const short* __restrict__ Vt, const int* __restrict__ mask,
    float* __restrict__ out) {
  const int lane = threadIdx.x & 63, wid = threadIdx.x >> 6;  // wid = head
  const int lrow = lane & 15, lq = lane >> 4;
  const int id = blockIdx.x;
  const int bt = ((id & 7) << 1) + ((id >> 3) & 1);  // cluster 2 bt per XCD
  const int q0 = (id >> 4) * 16;
  const int L = mask[bt];
  const int h = wid;

  __shared__ __align__(16) short qx[16 * 264];        // Q tile -> X tile
  __shared__ __align__(16) unsigned int ptbuf[8][16 * 36];  // per-wave P^T
  unsigned int* ptg = &ptbuf[wid][0];

  // ---- phase 1: Q projection into LDS (own head's 32 cols) ----
  {
    const int n0 = h * 32;
    const float* X = query + ((size_t)bt * 1024 + q0) * 256;
    ffrag acc[2] = {};
#pragma unroll
    for (int k0 = 0; k0 < 256; k0 += 32) {
      bfrag a = cvt8(X + (size_t)lrow * 256 + k0 + lq * 8);
      bfrag b[2];
#pragma unroll
      for (int j = 0; j < 2; ++j)
        b[j] = cvt8(Wq + (size_t)(n0 + j * 16 + lrow) * 256 + k0 + lq * 8);
#pragma unroll
      for (int j = 0; j < 2; ++j)
        acc[j] = __builtin_amdgcn_mfma_f32_16x16x32_bf16(a, b[j], acc[j], 0, 0, 0);
    }
#pragma unroll
    for (int j = 0; j < 2; ++j) {
      int d = n0 + j * 16 + lrow;
      float bs = bq[d];
#pragma unroll
      for (int r = 0; r < 4; ++r)
        qx[(lq * 4 + r) * 264 + d] = f2bf(acc[j][r] + bs);
    }
  }
  // no barrier: wave reads only its own columns until phase 3

  // ---- phase 2: attention via S^T = K·Q^T; o,l are linear in chunks ----
  const short* Kb = K + (size_t)bt * 262144;            // [1024][256]
  const short* Vb = Vt + ((size_t)bt * 8 + h) * 32768;  // [32][1024]
  bfrag qf = *(const bfrag*)(qx + lrow * 264 + h * 32 + lq * 8);

  const int nvalid = min(max(L - q0, 0), 16);
  const int nchunk = (nvalid > 0) ? ((L + 63) >> 6) : 0;
  const int nc0 = (nchunk + 1) >> 1;

  float l_loc[2] = {0.f, 0.f};
  ffrag o[2] = {};  // o[dj] = O^T[d-block dj][qrow lrow]

  auto do_chunk = [&](int kc, int li) {
    const ffrag zf = {0.f, 0.f, 0.f, 0.f};
    bfrag kf[4];
#pragma unroll
    for (int f = 0; f < 4; ++f)
      kf[f] = *(const bfrag*)(Kb + (size_t)(kc + f * 16 + lrow) * 256 + h * 32 + lq * 8);
    bfrag av[2][2];
#pragma unroll
    for (int dj = 0; dj < 2; ++dj)
#pragma unroll
      for (int b = 0; b < 2; ++b)
        av[dj][b] = *(const bfrag*)(Vb + (size_t)(dj * 16 + lrow) * 1024 + kc + b * 32 + lq * 8);
    ffrag st[4];
#pragma unroll
    for (int f = 0; f < 4; ++f)
      st[f] = __builtin_amdgcn_mfma_f32_16x16x32_bf16(kf[f], qf, zf, 0, 0, 0);
    float p[4][4];
    if (kc + 64 <= L) {
#pragma unroll
      for (int f = 0; f < 4; ++f)
#pragma unroll
        for (int r = 0; r < 4; ++r) {
          p[f][r] = exp2f(st[f][r] * EXPC);
          l_loc[li] += p[f][r];
        }
    } else {
#pragma unroll
      for (int f = 0; f < 4; ++f)
#pragma unroll
        for (int r = 0; r < 4; ++r) {
          int kr = kc + f * 16 + lq * 4 + r;
          float pv = (kr < L) ? exp2f(st[f][r] * EXPC) : 0.f;
          p[f][r] = pv;
          l_loc[li] += pv;
        }
    }
#pragma unroll
    for (int f = 0; f < 4; ++f) {
      u2v w;
      w[0] = packbf(p[f][0], p[f][1]);
      w[1] = packbf(p[f][2], p[f][3]);
      *(u2v*)(ptg + lrow * 36 + 8 * f + 2 * lq) = w;  // ds_write_b64
    }
#pragma unroll
    for (int b = 0; b < 2; ++b) {
      u4v pv = *(const u4v*)(ptg + lrow * 36 + 16 * b + 4 * lq);  // ds_read_b128
      union { u4v u; bfrag bf; } pt; pt.u = pv;
#pragma unroll
      for (int dj = 0; dj < 2; ++dj)
        o[dj] = __builtin_amdgcn_mfma_f32_16x16x32_bf16(av[dj][b], pt.bf, o[dj], 0, 0, 0);
    }
  };

#pragma unroll 1
  for (int tt = 0; tt < nc0; ++tt) {
    do_chunk(tt * 64, 0);
    const int c1 = nc0 + tt;
    if (c1 < nchunk) do_chunk(c1 * 64, 1);
  }

  // row-sum l: per-lane partials over lq; reduce the 4 quads
  float l_i;
  {
    float rs = l_loc[0] + l_loc[1];
    rs += __shfl_xor(rs, 16);
    rs += __shfl_xor(rs, 32);
    l_i = rs;
  }

  // ---- tail: invalid q rows -> x = (1/1024) * colsum(V) (exact vs reference) ----
  if (nvalid < 16) {
    if (lrow >= nvalid) {
      l_i = 1024.f;
#pragma unroll
      for (int dj = 0; dj < 2; ++dj)
#pragma unroll
        for (int r = 0; r < 4; ++r) o[dj][r] = 0.f;
    }
    bfrag ind;
    {
      short iv = (lrow >= nvalid) ? (short)0x3F80 : (short)0;  // bf16 1.0
#pragma unroll
      for (int j = 0; j < 8; ++j) ind[j] = iv;
    }
#pragma unroll 1
    for (int kc = 0; kc < 1024; kc += 64)
#pragma unroll
      for (int dj = 0; dj < 2; ++dj)
#pragma unroll
        for (int b = 0; b < 2; ++b) {
          bfrag av = *(const bfrag*)(Vb + (size_t)(dj * 16 + lrow) * 1024 + kc + b * 32 + lq * 8);
          o[dj] = __builtin_amdgcn_mfma_f32_16x16x32_bf16(av, ind, o[dj], 0, 0, 0);
        }
  }

  // write x into qx: lane holds qrow = lrow, d = dj*16 + 4*lq + r
  {
    float rcp = 1.0f / l_i;
#pragma unroll
    for (int dj = 0; dj < 2; ++dj) {
      u2v w;
      w[0] = packbf(o[dj][0] * rcp, o[dj][1] * rcp);
      w[1] = packbf(o[dj][2] * rcp, o[dj][3] * rcp);
      short* dst = qx + lrow * 264 + h * 32 + dj * 16 + lq * 4;
      *(u2v*)dst = w;  // 8B store
    }
  }
  __syncthreads();

  // ---- phase 3: output projection; wave computes cols wid*32..+31 ----
  {
    const int n0 = h * 32;
    ffrag acc[2] = {};
#pragma unroll
    for (int k0 = 0; k0 < 256; k0 += 32) {
      bfrag a = *(const bfrag*)(qx + lrow * 264 + k0 + lq * 8);
      bfrag b[2];
#pragma unroll
      for (int j = 0; j < 2; ++j)
        b[j] = cvt8(Wo + (size_t)(n0 + j * 16 + lrow) * 256 + k0 + lq * 8);
#pragma unroll
      for (int j = 0; j < 2; ++j)
        acc[j] = __builtin_amdgcn_mfma_f32_16x16x32_bf16(a, b[j], acc[j], 0, 0, 0);
    }
#pragma unroll
    for (int j = 0; j < 2; ++j) {
      int d = n0 + j * 16 + lrow;
      float bs = bo[d];
#pragma unroll
      for (int r = 0; r < 4; ++r)
        out[((size_t)bt * 1024 + q0 + lq * 4 + r) * 256 + d] = acc[j][r] + bs;
    }
  }
}

extern "C" void kernel_launch(void* const* d_in, const int* in_sizes, int n_in,
                              void* d_out, int out_size, void* d_ws, size_t ws_size,
                              hipStream_t stream) {
  const float* query = (const float*)d_in[0];
  const float* key   = (const float*)d_in[1];
  const float* value = (const float*)d_in[2];
  const int*   mask  = (const int*)d_in[3];
  const float* Wq = (const float*)d_in[4];
  const float* bq = (const float*)d_in[5];
  const float* Wk = (const float*)d_in[6];
  const float* bk = (const float*)d_in[7];
  const float* Wv = (const float*)d_in[8];
  const float* bv = (const float*)d_in[9];
  const float* Wo = (const float*)d_in[10];
  const float* bo = (const float*)d_in[11];
  float* out = (float*)d_out;

  // workspace: K bf16 (8 MB) + Vt bf16 (8 MB) = 16,777,216 bytes exactly
  short* k_ws  = (short*)d_ws;
  short* vt_ws = k_ws + 4194304;

  proj_kv<<<dim3(512), 256, 0, stream>>>(key, Wk, bk, value, Wv, bv, k_ws, vt_ws);
  attn_fused<<<dim3(1024), 512, 0, stream>>>(query, Wq, bq, Wo, bo,
                                             k_ws, vt_ws, mask, out);
}

// Round 7
// 296.811 us; speedup vs baseline: 1.0021x; 1.0021x over previous
//
#include <hip/hip_runtime.h>

#define EXPC 0.25505654442163f  // (1/sqrt(32)) * log2(e)

typedef __attribute__((ext_vector_type(8))) short bfrag;   // 8 bf16
typedef __attribute__((ext_vector_type(4))) float ffrag;   // 4 f32 acc
typedef __attribute__((ext_vector_type(8))) unsigned int u8v;
typedef __attribute__((ext_vector_type(4))) unsigned int u4v;
typedef __attribute__((ext_vector_type(2))) unsigned int u2v;

__device__ __forceinline__ short f2bf(float x) {
  union { float f; unsigned u; } v; v.f = x;
  return (short)((v.u + 0x8000u) >> 16);  // round-half-up
}

__device__ __forceinline__ unsigned int packbf(float a, float b) {
  return __builtin_amdgcn_perm(__float_as_uint(b) + 0x8000u,
                               __float_as_uint(a) + 0x8000u, 0x07060302u);
}

__device__ __forceinline__ bfrag cvtp(u8v x) {
  u4v r;
#pragma unroll
  for (int i = 0; i < 4; ++i)
    r[i] = __builtin_amdgcn_perm(x[2 * i + 1] + 0x8000u, x[2 * i] + 0x8000u, 0x07060302u);
  union { u4v u; bfrag b; } c; c.u = r; return c.b;
}
__device__ __forceinline__ bfrag cvt8(const float* __restrict__ p) {
  return cvtp(*(const u8v*)p);
}

// ---- fused K+V projection, LDS-staged (kept from R6 — rest dropped 135->105us) ----
// blocks 0..255:  K: C[64 kin-rows][256 d] -> ko[16384][256]
// blocks 256..511: V: C[256 d][64 vin-rows] -> vt[bt][256][1024] (transposed)
__global__ __launch_bounds__(256, 3) void proj_kv(
    const float* __restrict__ kin, const float* __restrict__ Wk,
    const float* __restrict__ bk, const float* __restrict__ vin,
    const float* __restrict__ Wv, const float* __restrict__ bv,
    short* __restrict__ ko, short* __restrict__ vt) {
  const int t = threadIdx.x;
  const int lane = t & 63, wid = t >> 6;
  const int lrow = lane & 15, lq = lane >> 4;
  __shared__ __align__(16) char lds[40960];
  short* Ab = (short*)lds;
  short* Bb = (short*)(lds + 20480);
  short* tile = (short*)lds;

  const bool isK = blockIdx.x < 256;
  const int bx = isK ? blockIdx.x : blockIdx.x - 256;
  const int m0 = bx * 64;
  const int row4 = t >> 2, c4 = (t & 3) * 8;

  ffrag acc[4][4] = {};
#pragma unroll 1
  for (int s = 0; s < 8; ++s) {
    const int k0 = s * 32;
    if (s) __syncthreads();
    if (isK) {
      *(bfrag*)(Ab + row4 * 40 + c4) =
          cvt8(kin + (size_t)(m0 + row4) * 256 + k0 + c4);
#pragma unroll
      for (int seg = 0; seg < 4; ++seg)
        *(bfrag*)(Bb + (seg * 64 + row4) * 40 + c4) =
            cvt8(Wk + (size_t)(seg * 64 + row4) * 256 + k0 + c4);
    } else {
      *(bfrag*)(Bb + row4 * 40 + c4) =
          cvt8(vin + (size_t)(m0 + row4) * 256 + k0 + c4);
#pragma unroll
      for (int seg = 0; seg < 4; ++seg)
        *(bfrag*)(Ab + (seg * 64 + row4) * 40 + c4) =
            cvt8(Wv + (size_t)(seg * 64 + row4) * 256 + k0 + c4);
    }
    __syncthreads();
    bfrag a[4], b[4];
    if (isK) {
#pragma unroll
      for (int i = 0; i < 4; ++i)
        a[i] = *(const bfrag*)(Ab + (i * 16 + lrow) * 40 + lq * 8);
#pragma unroll
      for (int j = 0; j < 4; ++j)
        b[j] = *(const bfrag*)(Bb + (wid * 64 + j * 16 + lrow) * 40 + lq * 8);
    } else {
#pragma unroll
      for (int i = 0; i < 4; ++i)
        a[i] = *(const bfrag*)(Ab + (wid * 64 + i * 16 + lrow) * 40 + lq * 8);
#pragma unroll
      for (int j = 0; j < 4; ++j)
        b[j] = *(const bfrag*)(Bb + (j * 16 + lrow) * 40 + lq * 8);
    }
#pragma unroll
    for (int i = 0; i < 4; ++i)
#pragma unroll
      for (int j = 0; j < 4; ++j)
        acc[i][j] = __builtin_amdgcn_mfma_f32_16x16x32_bf16(a[i], b[j], acc[i][j], 0, 0, 0);
  }
  __syncthreads();

  if (isK) {
#pragma unroll
    for (int j = 0; j < 4; ++j) {
      int d = wid * 64 + j * 16 + lrow;
      float bs = bk[d];
#pragma unroll
      for (int i = 0; i < 4; ++i)
#pragma unroll
        for (int r = 0; r < 4; ++r)
          tile[(i * 16 + lq * 4 + r) * 264 + d] = f2bf(acc[i][j][r] + bs);
    }
    __syncthreads();
#pragma unroll
    for (int p = 0; p < 8; ++p) {
      int row = p * 8 + (t >> 5), c = t & 31;
      bfrag v = *(const bfrag*)(tile + row * 264 + c * 8);
      *(bfrag*)(ko + (size_t)(m0 + row) * 256 + c * 8) = v;
    }
  } else {
#pragma unroll
    for (int i = 0; i < 4; ++i)
#pragma unroll
      for (int r = 0; r < 4; ++r) {
        int d = wid * 64 + i * 16 + lq * 4 + r;
        float bs = bv[d];
#pragma unroll
        for (int j = 0; j < 4; ++j)
          tile[d * 72 + j * 16 + lrow] = f2bf(acc[i][j][r] + bs);
      }
    __syncthreads();
    const int bt = m0 >> 10, sl0 = m0 & 1023;
#pragma unroll
    for (int p = 0; p < 8; ++p) {
      int d = p * 32 + (t >> 3), c = t & 7;
      bfrag v = *(const bfrag*)(tile + d * 72 + c * 8);
      *(bfrag*)(vt + (size_t)bt * 262144 + (size_t)d * 1024 + sl0 + c * 8) = v;
    }
  }
}

// ---- fused: Q-proj -> attention (S^T, 2 g-streams, software-pipelined) -> out-proj ----
// grid 512 x 512 thr; 32 q-rows/block; wave = 1 head; separate P buffer per g-stream.
__global__ __launch_bounds__(512, 4) void attn_fused(
    const float* __restrict__ query, const float* __restrict__ Wq,
    const float* __restrict__ bq, const float* __restrict__ Wo,
    const float* __restrict__ bo, const short* __restrict__ K,
    const short* __restrict__ Vt, const int* __restrict__ mask,
    float* __restrict__ out) {
  const int lane = threadIdx.x & 63, wid = threadIdx.x >> 6;  // wid = head
  const int lrow = lane & 15, lq = lane >> 4;
  const int id = blockIdx.x;
  const int bt = ((id & 7) << 1) + ((id >> 3) & 1);  // cluster 2 bt per XCD
  const int q0 = (id >> 4) * 32;
  const int L = mask[bt];
  const int h = wid;

  __shared__ __align__(16) short qx[32 * 264];                 // Q tile -> X tile
  __shared__ __align__(16) unsigned int ptbuf[8][2][16 * 36];  // per-wave, PER-STREAM P^T

  // ---- phase 1: Q projection into LDS (own head's 32 cols) ----
  {
    const int n0 = h * 32;
    const float* X = query + ((size_t)bt * 1024 + q0) * 256;
    ffrag acc[2][2] = {};
#pragma unroll
    for (int k0 = 0; k0 < 256; k0 += 32) {
      bfrag a[2], b[2];
#pragma unroll
      for (int i = 0; i < 2; ++i)
        a[i] = cvt8(X + (size_t)(i * 16 + lrow) * 256 + k0 + lq * 8);
#pragma unroll
      for (int j = 0; j < 2; ++j)
        b[j] = cvt8(Wq + (size_t)(n0 + j * 16 + lrow) * 256 + k0 + lq * 8);
#pragma unroll
      for (int i = 0; i < 2; ++i)
#pragma unroll
        for (int j = 0; j < 2; ++j)
          acc[i][j] = __builtin_amdgcn_mfma_f32_16x16x32_bf16(a[i], b[j], acc[i][j], 0, 0, 0);
    }
#pragma unroll
    for (int j = 0; j < 2; ++j) {
      int d = n0 + j * 16 + lrow;
      float bs = bq[d];
#pragma unroll
      for (int i = 0; i < 2; ++i)
#pragma unroll
        for (int r = 0; r < 4; ++r)
          qx[(i * 16 + lq * 4 + r) * 264 + d] = f2bf(acc[i][j][r] + bs);
    }
  }
  // no barrier: wave reads only its own columns until phase 3

  // ---- phase 2: S^T = K·Q^T, pipelined: prefetch kf(c+1), av(c); PV lags one chunk ----
  const short* Kb = K + (size_t)bt * 262144;            // [1024][256]
  const short* Vb = Vt + ((size_t)bt * 8 + h) * 32768;  // [32][1024]
  bfrag qf[2];
#pragma unroll
  for (int g = 0; g < 2; ++g)
    qf[g] = *(const bfrag*)(qx + (g * 16 + lrow) * 264 + h * 32 + lq * 8);

  const int nvalid = min(max(L - q0, 0), 32);
  const int nchunk = (nvalid > 0) ? ((L + 63) >> 6) : 0;

  float l_loc[2] = {0.f, 0.f};
  ffrag o[2][2] = {};  // o[g][dj]

  bfrag kf_c[4], kf_n[4], av_c[2][2], av_p[2][2];
  if (nchunk > 0) {
#pragma unroll
    for (int f = 0; f < 4; ++f)
      kf_c[f] = *(const bfrag*)(Kb + (size_t)(f * 16 + lrow) * 256 + h * 32 + lq * 8);
  }

#pragma unroll 1
  for (int c = 0; c < nchunk; ++c) {
    const int kc = c * 64;
    // read P(c-1) first (in-order LDS: sees last iter's write; wait lands at PV below)
    u4v pr[2][2];
    if (c) {
#pragma unroll
      for (int g = 0; g < 2; ++g)
#pragma unroll
        for (int b = 0; b < 2; ++b)
          pr[g][b] = *(const u4v*)(&ptbuf[wid][g][0] + lrow * 36 + 16 * b + 4 * lq);
    }
    // prefetch kf(c+1); load av(c) (used by PV at iter c+1)
    if (c + 1 < nchunk) {
#pragma unroll
      for (int f = 0; f < 4; ++f)
        kf_n[f] = *(const bfrag*)(Kb + (size_t)(kc + 64 + f * 16 + lrow) * 256 + h * 32 + lq * 8);
    }
#pragma unroll
    for (int dj = 0; dj < 2; ++dj)
#pragma unroll
      for (int b = 0; b < 2; ++b)
        av_c[dj][b] = *(const bfrag*)(Vb + (size_t)(dj * 16 + lrow) * 1024 + kc + b * 32 + lq * 8);

    // QK for both g (kf_c loaded a full iteration ago)
    const ffrag zf = {0.f, 0.f, 0.f, 0.f};
    ffrag st[2][4];
#pragma unroll
    for (int g = 0; g < 2; ++g)
#pragma unroll
      for (int f = 0; f < 4; ++f)
        st[g][f] = __builtin_amdgcn_mfma_f32_16x16x32_bf16(kf_c[f], qf[g], zf, 0, 0, 0);

    // exp / mask / pack
    const bool fullc = (kc + 64 <= L);
    u2v w[2][4];
#pragma unroll
    for (int g = 0; g < 2; ++g)
#pragma unroll
      for (int f = 0; f < 4; ++f) {
        float p[4];
        if (fullc) {
#pragma unroll
          for (int r = 0; r < 4; ++r) {
            p[r] = exp2f(st[g][f][r] * EXPC);
            l_loc[g] += p[r];
          }
        } else {
#pragma unroll
          for (int r = 0; r < 4; ++r) {
            int kr = kc + f * 16 + lq * 4 + r;
            p[r] = (kr < L) ? exp2f(st[g][f][r] * EXPC) : 0.f;
            l_loc[g] += p[r];
          }
        }
        w[g][f][0] = packbf(p[0], p[1]);
        w[g][f][1] = packbf(p[2], p[3]);
      }

    // PV(c-1) with av_p (loaded at iter c-1) and pr (read at top)
    if (c) {
#pragma unroll
      for (int g = 0; g < 2; ++g)
#pragma unroll
        for (int b = 0; b < 2; ++b) {
          union { u4v u; bfrag bf; } pt; pt.u = pr[g][b];
#pragma unroll
          for (int dj = 0; dj < 2; ++dj)
            o[g][dj] = __builtin_amdgcn_mfma_f32_16x16x32_bf16(av_p[dj][b], pt.bf, o[g][dj], 0, 0, 0);
        }
    }

    // write P(c) (after the read of P(c-1): in-order LDS keeps it safe)
#pragma unroll
    for (int g = 0; g < 2; ++g)
#pragma unroll
      for (int f = 0; f < 4; ++f)
        *(u2v*)(&ptbuf[wid][g][0] + lrow * 36 + 8 * f + 2 * lq) = w[g][f];

    // rotate
#pragma unroll
    for (int f = 0; f < 4; ++f) kf_c[f] = kf_n[f];
#pragma unroll
    for (int dj = 0; dj < 2; ++dj)
#pragma unroll
      for (int b = 0; b < 2; ++b) av_p[dj][b] = av_c[dj][b];
  }
  // drain: PV for last chunk
  if (nchunk > 0) {
#pragma unroll
    for (int g = 0; g < 2; ++g)
#pragma unroll
      for (int b = 0; b < 2; ++b) {
        u4v pv = *(const u4v*)(&ptbuf[wid][g][0] + lrow * 36 + 16 * b + 4 * lq);
        union { u4v u; bfrag bf; } pt; pt.u = pv;
#pragma unroll
        for (int dj = 0; dj < 2; ++dj)
          o[g][dj] = __builtin_amdgcn_mfma_f32_16x16x32_bf16(av_p[dj][b], pt.bf, o[g][dj], 0, 0, 0);
      }
  }

  // row-sum l: per-lane partials; reduce across the 4 lane-quads
  float l_i[2];
#pragma unroll
  for (int g = 0; g < 2; ++g) {
    float rs = l_loc[g];
    rs += __shfl_xor(rs, 16);
    rs += __shfl_xor(rs, 32);
    l_i[g] = rs;
  }

  // ---- tail: invalid q rows -> x = (1/1024) * colsum(V) (exact vs reference) ----
  if (nvalid < 32) {
#pragma unroll
    for (int g = 0; g < 2; ++g) {
      bool inv = (g * 16 + lrow) >= nvalid;
      if (inv) {
        l_i[g] = 1024.f;
#pragma unroll
        for (int dj = 0; dj < 2; ++dj)
#pragma unroll
          for (int r = 0; r < 4; ++r) o[g][dj][r] = 0.f;
      }
    }
    bfrag ind[2];
#pragma unroll
    for (int g = 0; g < 2; ++g) {
      short iv = ((g * 16 + lrow) >= nvalid) ? (short)0x3F80 : (short)0;
#pragma unroll
      for (int j = 0; j < 8; ++j) ind[g][j] = iv;
    }
    const bool g0 = (nvalid < 16);
#pragma unroll 2
    for (int kc = 0; kc < 1024; kc += 64) {
#pragma unroll
      for (int dj = 0; dj < 2; ++dj)
#pragma unroll
        for (int b = 0; b < 2; ++b) {
          bfrag av = *(const bfrag*)(Vb + (size_t)(dj * 16 + lrow) * 1024 + kc + b * 32 + lq * 8);
          if (g0)
            o[0][dj] = __builtin_amdgcn_mfma_f32_16x16x32_bf16(av, ind[0], o[0][dj], 0, 0, 0);
          o[1][dj] = __builtin_amdgcn_mfma_f32_16x16x32_bf16(av, ind[1], o[1][dj], 0, 0, 0);
        }
    }
  }

  // write x into qx: lane holds qrow = g*16+lrow, d = dj*16 + 4*lq + r
#pragma unroll
  for (int g = 0; g < 2; ++g) {
    float rcp = 1.0f / l_i[g];
#pragma unroll
    for (int dj = 0; dj < 2; ++dj) {
      u2v w;
      w[0] = packbf(o[g][dj][0] * rcp, o[g][dj][1] * rcp);
      w[1] = packbf(o[g][dj][2] * rcp, o[g][dj][3] * rcp);
      short* dst = qx + (g * 16 + lrow) * 264 + h * 32 + dj * 16 + lq * 4;
      *(u2v*)dst = w;
    }
  }
  __syncthreads();

  // ---- phase 3: output projection; wave computes cols wid*32..+31 ----
  {
    const int n0 = h * 32;
    ffrag acc[2][2] = {};
#pragma unroll
    for (int k0 = 0; k0 < 256; k0 += 32) {
      bfrag a[2], b[2];
#pragma unroll
      for (int i = 0; i < 2; ++i)
        a[i] = *(const bfrag*)(qx + (i * 16 + lrow) * 264 + k0 + lq * 8);
#pragma unroll
      for (int j = 0; j < 2; ++j)
        b[j] = cvt8(Wo + (size_t)(n0 + j * 16 + lrow) * 256 + k0 + lq * 8);
#pragma unroll
      for (int i = 0; i < 2; ++i)
#pragma unroll
        for (int j = 0; j < 2; ++j)
          acc[i][j] = __builtin_amdgcn_mfma_f32_16x16x32_bf16(a[i], b[j], acc[i][j], 0, 0, 0);
    }
#pragma unroll
    for (int j = 0; j < 2; ++j) {
      int d = n0 + j * 16 + lrow;
      float bs = bo[d];
#pragma unroll
      for (int i = 0; i < 2; ++i)
#pragma unroll
        for (int r = 0; r < 4; ++r)
          out[((size_t)bt * 1024 + q0 + i * 16 + lq * 4 + r) * 256 + d] = acc[i][j][r] + bs;
    }
  }
}

extern "C" void kernel_launch(void* const* d_in, const int* in_sizes, int n_in,
                              void* d_out, int out_size, void* d_ws, size_t ws_size,
                              hipStream_t stream) {
  const float* query = (const float*)d_in[0];
  const float* key   = (const float*)d_in[1];
  const float* value = (const float*)d_in[2];
  const int*   mask  = (const int*)d_in[3];
  const float* Wq = (const float*)d_in[4];
  const float* bq = (const float*)d_in[5];
  const float* Wk = (const float*)d_in[6];
  const float* bk = (const float*)d_in[7];
  const float* Wv = (const float*)d_in[8];
  const float* bv = (const float*)d_in[9];
  const float* Wo = (const float*)d_in[10];
  const float* bo = (const float*)d_in[11];
  float* out = (float*)d_out;

  // workspace: K bf16 (8 MB) + Vt bf16 (8 MB) = 16,777,216 bytes exactly
  short* k_ws  = (short*)d_ws;
  short* vt_ws = k_ws + 4194304;

  proj_kv<<<dim3(512), 256, 0, stream>>>(key, Wk, bk, value, Wv, bv, k_ws, vt_ws);
  attn_fused<<<dim3(512), 512, 0, stream>>>(query, Wq, bq, Wo, bo,
                                            k_ws, vt_ws, mask, out);
}

// Round 8
// 275.141 us; speedup vs baseline: 1.0810x; 1.0788x over previous
//
#include <hip/hip_runtime.h>

#define EXPC 0.25505654442163f  // (1/sqrt(32)) * log2(e)

typedef __attribute__((ext_vector_type(8))) short bfrag;   // 8 bf16
typedef __attribute__((ext_vector_type(4))) float ffrag;   // 4 f32 acc
typedef __attribute__((ext_vector_type(8))) unsigned int u8v;
typedef __attribute__((ext_vector_type(4))) unsigned int u4v;
typedef __attribute__((ext_vector_type(2))) unsigned int u2v;

__device__ __forceinline__ short f2bf(float x) {
  union { float f; unsigned u; } v; v.f = x;
  return (short)((v.u + 0x8000u) >> 16);  // round-half-up
}

__device__ __forceinline__ unsigned int packbf(float a, float b) {
  return __builtin_amdgcn_perm(__float_as_uint(b) + 0x8000u,
                               __float_as_uint(a) + 0x8000u, 0x07060302u);
}

__device__ __forceinline__ bfrag cvtp(u8v x) {
  u4v r;
#pragma unroll
  for (int i = 0; i < 4; ++i)
    r[i] = __builtin_amdgcn_perm(x[2 * i + 1] + 0x8000u, x[2 * i] + 0x8000u, 0x07060302u);
  union { u4v u; bfrag b; } c; c.u = r; return c.b;
}
__device__ __forceinline__ bfrag cvt8(const float* __restrict__ p) {
  return cvtp(*(const u8v*)p);
}

// ---- fused K+V projection, LDS-staged (verbatim from R6; rest = ~105us) ----
__global__ __launch_bounds__(256, 3) void proj_kv(
    const float* __restrict__ kin, const float* __restrict__ Wk,
    const float* __restrict__ bk, const float* __restrict__ vin,
    const float* __restrict__ Wv, const float* __restrict__ bv,
    short* __restrict__ ko, short* __restrict__ vt) {
  const int t = threadIdx.x;
  const int lane = t & 63, wid = t >> 6;
  const int lrow = lane & 15, lq = lane >> 4;
  __shared__ __align__(16) char lds[40960];
  short* Ab = (short*)lds;
  short* Bb = (short*)(lds + 20480);
  short* tile = (short*)lds;

  const bool isK = blockIdx.x < 256;
  const int bx = isK ? blockIdx.x : blockIdx.x - 256;
  const int m0 = bx * 64;
  const int row4 = t >> 2, c4 = (t & 3) * 8;

  ffrag acc[4][4] = {};
#pragma unroll 1
  for (int s = 0; s < 8; ++s) {
    const int k0 = s * 32;
    if (s) __syncthreads();
    if (isK) {
      *(bfrag*)(Ab + row4 * 40 + c4) =
          cvt8(kin + (size_t)(m0 + row4) * 256 + k0 + c4);
#pragma unroll
      for (int seg = 0; seg < 4; ++seg)
        *(bfrag*)(Bb + (seg * 64 + row4) * 40 + c4) =
            cvt8(Wk + (size_t)(seg * 64 + row4) * 256 + k0 + c4);
    } else {
      *(bfrag*)(Bb + row4 * 40 + c4) =
          cvt8(vin + (size_t)(m0 + row4) * 256 + k0 + c4);
#pragma unroll
      for (int seg = 0; seg < 4; ++seg)
        *(bfrag*)(Ab + (seg * 64 + row4) * 40 + c4) =
            cvt8(Wv + (size_t)(seg * 64 + row4) * 256 + k0 + c4);
    }
    __syncthreads();
    bfrag a[4], b[4];
    if (isK) {
#pragma unroll
      for (int i = 0; i < 4; ++i)
        a[i] = *(const bfrag*)(Ab + (i * 16 + lrow) * 40 + lq * 8);
#pragma unroll
      for (int j = 0; j < 4; ++j)
        b[j] = *(const bfrag*)(Bb + (wid * 64 + j * 16 + lrow) * 40 + lq * 8);
    } else {
#pragma unroll
      for (int i = 0; i < 4; ++i)
        a[i] = *(const bfrag*)(Ab + (wid * 64 + i * 16 + lrow) * 40 + lq * 8);
#pragma unroll
      for (int j = 0; j < 4; ++j)
        b[j] = *(const bfrag*)(Bb + (j * 16 + lrow) * 40 + lq * 8);
    }
#pragma unroll
    for (int i = 0; i < 4; ++i)
#pragma unroll
      for (int j = 0; j < 4; ++j)
        acc[i][j] = __builtin_amdgcn_mfma_f32_16x16x32_bf16(a[i], b[j], acc[i][j], 0, 0, 0);
  }
  __syncthreads();

  if (isK) {
#pragma unroll
    for (int j = 0; j < 4; ++j) {
      int d = wid * 64 + j * 16 + lrow;
      float bs = bk[d];
#pragma unroll
      for (int i = 0; i < 4; ++i)
#pragma unroll
        for (int r = 0; r < 4; ++r)
          tile[(i * 16 + lq * 4 + r) * 264 + d] = f2bf(acc[i][j][r] + bs);
    }
    __syncthreads();
#pragma unroll
    for (int p = 0; p < 8; ++p) {
      int row = p * 8 + (t >> 5), c = t & 31;
      bfrag v = *(const bfrag*)(tile + row * 264 + c * 8);
      *(bfrag*)(ko + (size_t)(m0 + row) * 256 + c * 8) = v;
    }
  } else {
#pragma unroll
    for (int i = 0; i < 4; ++i)
#pragma unroll
      for (int r = 0; r < 4; ++r) {
        int d = wid * 64 + i * 16 + lq * 4 + r;
        float bs = bv[d];
#pragma unroll
        for (int j = 0; j < 4; ++j)
          tile[d * 72 + j * 16 + lrow] = f2bf(acc[i][j][r] + bs);
      }
    __syncthreads();
    const int bt = m0 >> 10, sl0 = m0 & 1023;
#pragma unroll
    for (int p = 0; p < 8; ++p) {
      int d = p * 32 + (t >> 3), c = t & 7;
      bfrag v = *(const bfrag*)(tile + d * 72 + c * 8);
      *(bfrag*)(vt + (size_t)bt * 262144 + (size_t)d * 1024 + sl0 + c * 8) = v;
    }
  }
}

// ---- fused: Q-proj -> attention (S^T; 16 waves = 8 heads x 2 K-streams) -> out-proj ----
// grid 512 x 1024 thr; 32 q-rows/block; bt interleaved across consecutive blocks.
__global__ __launch_bounds__(1024, 4) void attn_fused(
    const float* __restrict__ query, const float* __restrict__ Wq,
    const float* __restrict__ bq, const float* __restrict__ Wo,
    const float* __restrict__ bo, const short* __restrict__ K,
    const short* __restrict__ Vt, const int* __restrict__ mask,
    float* __restrict__ out) {
  const int lane = threadIdx.x & 63, wid = threadIdx.x >> 6;  // 16 waves
  const int lrow = lane & 15, lq = lane >> 4;
  const int h = wid & 7, par = wid >> 3;
  const int id = blockIdx.x;
  const int bt = id & 15;          // interleave bt -> balances L across CUs
  const int q0 = (id >> 4) * 32;
  const int L = mask[bt];

  __shared__ __align__(16) short qx[32 * 264];               // 16.9 KB: Q tile -> X tile
  __shared__ __align__(16) unsigned int ptbuf[16][16 * 36];  // 36.9 KB: per-wave P^T
  unsigned int* ptg = &ptbuf[wid][0];
  float* mb = (float*)&ptbuf[0][0];  // merge region (reused post-barrier)

  // ---- phase 1: Q projection into LDS; wave computes cols wid*16..+15 ----
  {
    const int n0 = wid * 16;
    const float* X = query + ((size_t)bt * 1024 + q0) * 256;
    ffrag acc[2] = {};
#pragma unroll
    for (int k0 = 0; k0 < 256; k0 += 32) {
      bfrag b = cvt8(Wq + (size_t)(n0 + lrow) * 256 + k0 + lq * 8);
#pragma unroll
      for (int i = 0; i < 2; ++i) {
        bfrag a = cvt8(X + (size_t)(i * 16 + lrow) * 256 + k0 + lq * 8);
        acc[i] = __builtin_amdgcn_mfma_f32_16x16x32_bf16(a, b, acc[i], 0, 0, 0);
      }
    }
    float bs = bq[n0 + lrow];
#pragma unroll
    for (int i = 0; i < 2; ++i)
#pragma unroll
      for (int r = 0; r < 4; ++r)
        qx[(i * 16 + lq * 4 + r) * 264 + n0 + lrow] = f2bf(acc[i][r] + bs);
  }
  __syncthreads();

  // ---- phase 2: S^T = K·Q^T; wave (h, par) takes chunks c ≡ par (mod 2) ----
  const short* Kb = K + (size_t)bt * 262144;            // [1024][256]
  const short* Vb = Vt + ((size_t)bt * 8 + h) * 32768;  // [32][1024]
  bfrag qf[2];
#pragma unroll
  for (int g = 0; g < 2; ++g)
    qf[g] = *(const bfrag*)(qx + (g * 16 + lrow) * 264 + h * 32 + lq * 8);

  const int nvalid = min(max(L - q0, 0), 32);
  const int nchunk = (nvalid > 0) ? ((L + 63) >> 6) : 0;

  float l_loc[2] = {0.f, 0.f};
  ffrag o[2][2] = {};  // o[g][dj] partial over this wave's chunks

#pragma unroll 1
  for (int c = par; c < nchunk; c += 2) {
    const int kc = c * 64;
    const ffrag zf = {0.f, 0.f, 0.f, 0.f};
    bfrag kf[4];
#pragma unroll
    for (int f = 0; f < 4; ++f)
      kf[f] = *(const bfrag*)(Kb + (size_t)(kc + f * 16 + lrow) * 256 + h * 32 + lq * 8);
    bfrag av[2][2];
#pragma unroll
    for (int dj = 0; dj < 2; ++dj)
#pragma unroll
      for (int b = 0; b < 2; ++b)
        av[dj][b] = *(const bfrag*)(Vb + (size_t)(dj * 16 + lrow) * 1024 + kc + b * 32 + lq * 8);

    // QK for both g first (independent MFMA streams)
    ffrag st[2][4];
#pragma unroll
    for (int g = 0; g < 2; ++g)
#pragma unroll
      for (int f = 0; f < 4; ++f)
        st[g][f] = __builtin_amdgcn_mfma_f32_16x16x32_bf16(kf[f], qf[g], zf, 0, 0, 0);

    const bool fullc = (kc + 64 <= L);
#pragma unroll
    for (int g = 0; g < 2; ++g) {
      float p[4][4];
      if (fullc) {
#pragma unroll
        for (int f = 0; f < 4; ++f)
#pragma unroll
          for (int r = 0; r < 4; ++r) {
            p[f][r] = exp2f(st[g][f][r] * EXPC);
            l_loc[g] += p[f][r];
          }
      } else {
#pragma unroll
        for (int f = 0; f < 4; ++f)
#pragma unroll
          for (int r = 0; r < 4; ++r) {
            int kr = kc + f * 16 + lq * 4 + r;
            float pv = (kr < L) ? exp2f(st[g][f][r] * EXPC) : 0.f;
            p[f][r] = pv;
            l_loc[g] += pv;
          }
      }
      // P^T -> shared per-wave buffer (in-order wave LDS: write->read->overwrite safe)
#pragma unroll
      for (int f = 0; f < 4; ++f) {
        u2v w;
        w[0] = packbf(p[f][0], p[f][1]);
        w[1] = packbf(p[f][2], p[f][3]);
        *(u2v*)(ptg + lrow * 36 + 8 * f + 2 * lq) = w;
      }
#pragma unroll
      for (int b = 0; b < 2; ++b) {
        u4v pv = *(const u4v*)(ptg + lrow * 36 + 16 * b + 4 * lq);
        union { u4v u; bfrag bf; } pt; pt.u = pv;
#pragma unroll
        for (int dj = 0; dj < 2; ++dj)
          o[g][dj] = __builtin_amdgcn_mfma_f32_16x16x32_bf16(av[dj][b], pt.bf, o[g][dj], 0, 0, 0);
      }
    }
  }

  // per-wave row-sum l (quad reduce: k spans the 4 lane-quads)
  float l_i[2];
#pragma unroll
  for (int g = 0; g < 2; ++g) {
    float rs = l_loc[g];
    rs += __shfl_xor(rs, 16);
    rs += __shfl_xor(rs, 32);
    l_i[g] = rs;
  }

  // ---- tail: invalid q rows -> colsum(V), split across par waves ----
  if (nvalid < 32) {
#pragma unroll
    for (int g = 0; g < 2; ++g) {
      bool inv = (g * 16 + lrow) >= nvalid;
      if (inv) {
        l_i[g] = par ? 0.f : 1024.f;  // merged sum = 1024
#pragma unroll
        for (int dj = 0; dj < 2; ++dj)
#pragma unroll
          for (int r = 0; r < 4; ++r) o[g][dj][r] = 0.f;
      }
    }
    bfrag ind[2];
#pragma unroll
    for (int g = 0; g < 2; ++g) {
      short iv = ((g * 16 + lrow) >= nvalid) ? (short)0x3F80 : (short)0;
#pragma unroll
      for (int j = 0; j < 8; ++j) ind[g][j] = iv;
    }
    const bool g0 = (nvalid < 16);
#pragma unroll 1
    for (int kc = par * 64; kc < 1024; kc += 128) {
#pragma unroll
      for (int dj = 0; dj < 2; ++dj)
#pragma unroll
        for (int b = 0; b < 2; ++b) {
          bfrag av = *(const bfrag*)(Vb + (size_t)(dj * 16 + lrow) * 1024 + kc + b * 32 + lq * 8);
          if (g0)
            o[0][dj] = __builtin_amdgcn_mfma_f32_16x16x32_bf16(av, ind[0], o[0][dj], 0, 0, 0);
          o[1][dj] = __builtin_amdgcn_mfma_f32_16x16x32_bf16(av, ind[1], o[1][dj], 0, 0, 0);
        }
    }
  }

  // ---- merge par=1 partials into par=0 through LDS (ptbuf reused, fp32) ----
  __syncthreads();  // all waves done with their P buffers
  if (par == 1) {
#pragma unroll
    for (int g = 0; g < 2; ++g) {
#pragma unroll
      for (int dj = 0; dj < 2; ++dj)
        *(ffrag*)(mb + h * 1024 + (g * 2 + dj) * 256 + lane * 4) = o[g][dj];
      if (lq == 0) mb[8192 + h * 32 + g * 16 + lrow] = l_i[g];
    }
  }
  __syncthreads();
  if (par == 0) {
#pragma unroll
    for (int g = 0; g < 2; ++g) {
#pragma unroll
      for (int dj = 0; dj < 2; ++dj) {
        ffrag pv = *(const ffrag*)(mb + h * 1024 + (g * 2 + dj) * 256 + lane * 4);
#pragma unroll
        for (int r = 0; r < 4; ++r) o[g][dj][r] += pv[r];
      }
      l_i[g] += mb[8192 + h * 32 + g * 16 + lrow];
    }
    // write x into qx: lane holds qrow = g*16+lrow, d = h*32 + dj*16 + 4*lq + r
#pragma unroll
    for (int g = 0; g < 2; ++g) {
      float rcp = 1.0f / l_i[g];
#pragma unroll
      for (int dj = 0; dj < 2; ++dj) {
        u2v w;
        w[0] = packbf(o[g][dj][0] * rcp, o[g][dj][1] * rcp);
        w[1] = packbf(o[g][dj][2] * rcp, o[g][dj][3] * rcp);
        short* dst = qx + (g * 16 + lrow) * 264 + h * 32 + dj * 16 + lq * 4;
        *(u2v*)dst = w;
      }
    }
  }
  __syncthreads();

  // ---- phase 3: output projection; wave computes cols wid*16..+15 ----
  {
    const int n0 = wid * 16;
    ffrag acc[2] = {};
#pragma unroll
    for (int k0 = 0; k0 < 256; k0 += 32) {
      bfrag b = cvt8(Wo + (size_t)(n0 + lrow) * 256 + k0 + lq * 8);
#pragma unroll
      for (int i = 0; i < 2; ++i) {
        bfrag a = *(const bfrag*)(qx + (i * 16 + lrow) * 264 + k0 + lq * 8);
        acc[i] = __builtin_amdgcn_mfma_f32_16x16x32_bf16(a, b, acc[i], 0, 0, 0);
      }
    }
    float bs = bo[n0 + lrow];
#pragma unroll
    for (int i = 0; i < 2; ++i)
#pragma unroll
      for (int r = 0; r < 4; ++r)
        out[((size_t)bt * 1024 + q0 + i * 16 + lq * 4 + r) * 256 + n0 + lrow] =
            acc[i][r] + bs;
  }
}

extern "C" void kernel_launch(void* const* d_in, const int* in_sizes, int n_in,
                              void* d_out, int out_size, void* d_ws, size_t ws_size,
                              hipStream_t stream) {
  const float* query = (const float*)d_in[0];
  const float* key   = (const float*)d_in[1];
  const float* value = (const float*)d_in[2];
  const int*   mask  = (const int*)d_in[3];
  const float* Wq = (const float*)d_in[4];
  const float* bq = (const float*)d_in[5];
  const float* Wk = (const float*)d_in[6];
  const float* bk = (const float*)d_in[7];
  const float* Wv = (const float*)d_in[8];
  const float* bv = (const float*)d_in[9];
  const float* Wo = (const float*)d_in[10];
  const float* bo = (const float*)d_in[11];
  float* out = (float*)d_out;

  // workspace: K bf16 (8 MB) + Vt bf16 (8 MB) = 16,777,216 bytes exactly
  short* k_ws  = (short*)d_ws;
  short* vt_ws = k_ws + 4194304;

  proj_kv<<<dim3(512), 256, 0, stream>>>(key, Wk, bk, value, Wv, bv, k_ws, vt_ws);
  attn_fused<<<dim3(512), 1024, 0, stream>>>(query, Wq, bq, Wo, bo,
                                             k_ws, vt_ws, mask, out);
}

// Round 9
// 222.822 us; speedup vs baseline: 1.3348x; 1.2348x over previous
//
#include <hip/hip_runtime.h>

#define EXPC 0.25505654442163f  // (1/sqrt(32)) * log2(e)

typedef __attribute__((ext_vector_type(8))) short bfrag;   // 8 bf16
typedef __attribute__((ext_vector_type(4))) float ffrag;   // 4 f32 acc
typedef __attribute__((ext_vector_type(8))) unsigned int u8v;
typedef __attribute__((ext_vector_type(4))) unsigned int u4v;
typedef __attribute__((ext_vector_type(2))) unsigned int u2v;

__device__ __forceinline__ short f2bf(float x) {
  union { float f; unsigned u; } v; v.f = x;
  return (short)((v.u + 0x8000u) >> 16);  // round-half-up
}

__device__ __forceinline__ unsigned int packbf(float a, float b) {
  return __builtin_amdgcn_perm(__float_as_uint(b) + 0x8000u,
                               __float_as_uint(a) + 0x8000u, 0x07060302u);
}

__device__ __forceinline__ bfrag cvtp(u8v x) {
  u4v r;
#pragma unroll
  for (int i = 0; i < 4; ++i)
    r[i] = __builtin_amdgcn_perm(x[2 * i + 1] + 0x8000u, x[2 * i] + 0x8000u, 0x07060302u);
  union { u4v u; bfrag b; } c; c.u = r; return c.b;
}
__device__ __forceinline__ bfrag cvt8(const float* __restrict__ p) {
  return cvtp(*(const u8v*)p);
}

// ---- fused K+V projection, LDS-staged (verbatim since R6) ----
__global__ __launch_bounds__(256, 3) void proj_kv(
    const float* __restrict__ kin, const float* __restrict__ Wk,
    const float* __restrict__ bk, const float* __restrict__ vin,
    const float* __restrict__ Wv, const float* __restrict__ bv,
    short* __restrict__ ko, short* __restrict__ vt) {
  const int t = threadIdx.x;
  const int lane = t & 63, wid = t >> 6;
  const int lrow = lane & 15, lq = lane >> 4;
  __shared__ __align__(16) char lds[40960];
  short* Ab = (short*)lds;
  short* Bb = (short*)(lds + 20480);
  short* tile = (short*)lds;

  const bool isK = blockIdx.x < 256;
  const int bx = isK ? blockIdx.x : blockIdx.x - 256;
  const int m0 = bx * 64;
  const int row4 = t >> 2, c4 = (t & 3) * 8;

  ffrag acc[4][4] = {};
#pragma unroll 1
  for (int s = 0; s < 8; ++s) {
    const int k0 = s * 32;
    if (s) __syncthreads();
    if (isK) {
      *(bfrag*)(Ab + row4 * 40 + c4) =
          cvt8(kin + (size_t)(m0 + row4) * 256 + k0 + c4);
#pragma unroll
      for (int seg = 0; seg < 4; ++seg)
        *(bfrag*)(Bb + (seg * 64 + row4) * 40 + c4) =
            cvt8(Wk + (size_t)(seg * 64 + row4) * 256 + k0 + c4);
    } else {
      *(bfrag*)(Bb + row4 * 40 + c4) =
          cvt8(vin + (size_t)(m0 + row4) * 256 + k0 + c4);
#pragma unroll
      for (int seg = 0; seg < 4; ++seg)
        *(bfrag*)(Ab + (seg * 64 + row4) * 40 + c4) =
            cvt8(Wv + (size_t)(seg * 64 + row4) * 256 + k0 + c4);
    }
    __syncthreads();
    bfrag a[4], b[4];
    if (isK) {
#pragma unroll
      for (int i = 0; i < 4; ++i)
        a[i] = *(const bfrag*)(Ab + (i * 16 + lrow) * 40 + lq * 8);
#pragma unroll
      for (int j = 0; j < 4; ++j)
        b[j] = *(const bfrag*)(Bb + (wid * 64 + j * 16 + lrow) * 40 + lq * 8);
    } else {
#pragma unroll
      for (int i = 0; i < 4; ++i)
        a[i] = *(const bfrag*)(Ab + (wid * 64 + i * 16 + lrow) * 40 + lq * 8);
#pragma unroll
      for (int j = 0; j < 4; ++j)
        b[j] = *(const bfrag*)(Bb + (j * 16 + lrow) * 40 + lq * 8);
    }
#pragma unroll
    for (int i = 0; i < 4; ++i)
#pragma unroll
      for (int j = 0; j < 4; ++j)
        acc[i][j] = __builtin_amdgcn_mfma_f32_16x16x32_bf16(a[i], b[j], acc[i][j], 0, 0, 0);
  }
  __syncthreads();

  if (isK) {
#pragma unroll
    for (int j = 0; j < 4; ++j) {
      int d = wid * 64 + j * 16 + lrow;
      float bs = bk[d];
#pragma unroll
      for (int i = 0; i < 4; ++i)
#pragma unroll
        for (int r = 0; r < 4; ++r)
          tile[(i * 16 + lq * 4 + r) * 264 + d] = f2bf(acc[i][j][r] + bs);
    }
    __syncthreads();
#pragma unroll
    for (int p = 0; p < 8; ++p) {
      int row = p * 8 + (t >> 5), c = t & 31;
      bfrag v = *(const bfrag*)(tile + row * 264 + c * 8);
      *(bfrag*)(ko + (size_t)(m0 + row) * 256 + c * 8) = v;
    }
  } else {
#pragma unroll
    for (int i = 0; i < 4; ++i)
#pragma unroll
      for (int r = 0; r < 4; ++r) {
        int d = wid * 64 + i * 16 + lq * 4 + r;
        float bs = bv[d];
#pragma unroll
        for (int j = 0; j < 4; ++j)
          tile[d * 72 + j * 16 + lrow] = f2bf(acc[i][j][r] + bs);
      }
    __syncthreads();
    const int bt = m0 >> 10, sl0 = m0 & 1023;
#pragma unroll
    for (int p = 0; p < 8; ++p) {
      int d = p * 32 + (t >> 3), c = t & 7;
      bfrag v = *(const bfrag*)(tile + d * 72 + c * 8);
      *(bfrag*)(vt + (size_t)bt * 262144 + (size_t)d * 1024 + sl0 + c * 8) = v;
    }
  }
}

// ---- fused: Q-proj(pre-scaled) -> attention (S^T, R5 shape, raw exp2) -> out-proj ----
// grid 512 x 512 thr; 32 q-rows/block; 1 head/wave, 2 g-streams; shared per-wave P buf.
__global__ __launch_bounds__(512, 4) void attn_fused(
    const float* __restrict__ query, const float* __restrict__ Wq,
    const float* __restrict__ bq, const float* __restrict__ Wo,
    const float* __restrict__ bo, const short* __restrict__ K,
    const short* __restrict__ Vt, const int* __restrict__ mask,
    float* __restrict__ out) {
  const int lane = threadIdx.x & 63, wid = threadIdx.x >> 6;  // wid = head
  const int lrow = lane & 15, lq = lane >> 4;
  const int id = blockIdx.x;
  const int bt = id & 15;          // interleave bt across blocks -> balanced L per CU
  const int q0 = (id >> 4) * 32;
  const int L = mask[bt];
  const int h = wid;

  __shared__ __align__(16) short qx[32 * 264];              // 16.9 KB: Q tile -> X tile
  __shared__ __align__(16) unsigned int ptbuf[8][16 * 36];  // 18.4 KB: per-wave P^T
  unsigned int* ptg = &ptbuf[wid][0];

  // ---- phase 1: Q projection into LDS, pre-scaled by EXPC (folds softmax scale) ----
  {
    const int n0 = h * 32;
    const float* X = query + ((size_t)bt * 1024 + q0) * 256;
    ffrag acc[2][2] = {};
#pragma unroll
    for (int k0 = 0; k0 < 256; k0 += 32) {
      bfrag a[2], b[2];
#pragma unroll
      for (int i = 0; i < 2; ++i)
        a[i] = cvt8(X + (size_t)(i * 16 + lrow) * 256 + k0 + lq * 8);
#pragma unroll
      for (int j = 0; j < 2; ++j)
        b[j] = cvt8(Wq + (size_t)(n0 + j * 16 + lrow) * 256 + k0 + lq * 8);
#pragma unroll
      for (int i = 0; i < 2; ++i)
#pragma unroll
        for (int j = 0; j < 2; ++j)
          acc[i][j] = __builtin_amdgcn_mfma_f32_16x16x32_bf16(a[i], b[j], acc[i][j], 0, 0, 0);
    }
#pragma unroll
    for (int j = 0; j < 2; ++j) {
      int d = n0 + j * 16 + lrow;
      float bs = bq[d];
#pragma unroll
      for (int i = 0; i < 2; ++i)
#pragma unroll
        for (int r = 0; r < 4; ++r)
          qx[(i * 16 + lq * 4 + r) * 264 + d] = f2bf((acc[i][j][r] + bs) * EXPC);
    }
  }
  // no barrier: wave reads only its own columns until phase 3

  // ---- phase 2: S^T = K·Q^T; p = v_exp_f32(st) directly (|st| small) ----
  const short* Kb = K + (size_t)bt * 262144;            // [1024][256]
  const short* Vb = Vt + ((size_t)bt * 8 + h) * 32768;  // [32][1024]
  bfrag qf[2];
#pragma unroll
  for (int g = 0; g < 2; ++g)
    qf[g] = *(const bfrag*)(qx + (g * 16 + lrow) * 264 + h * 32 + lq * 8);

  const int nvalid = min(max(L - q0, 0), 32);
  const int nchunk = (nvalid > 0) ? ((L + 63) >> 6) : 0;

  float l_loc[2] = {0.f, 0.f};
  ffrag o[2][2] = {};  // o[g][dj]

#pragma unroll 1
  for (int c = 0; c < nchunk; ++c) {
    const int kc = c * 64;
    const ffrag zf = {0.f, 0.f, 0.f, 0.f};
    bfrag kf[4];
#pragma unroll
    for (int f = 0; f < 4; ++f)
      kf[f] = *(const bfrag*)(Kb + (size_t)(kc + f * 16 + lrow) * 256 + h * 32 + lq * 8);
    bfrag av[2][2];
#pragma unroll
    for (int dj = 0; dj < 2; ++dj)
#pragma unroll
      for (int b = 0; b < 2; ++b)
        av[dj][b] = *(const bfrag*)(Vb + (size_t)(dj * 16 + lrow) * 1024 + kc + b * 32 + lq * 8);

    // QK for both g first (independent MFMA streams)
    ffrag st[2][4];
#pragma unroll
    for (int g = 0; g < 2; ++g)
#pragma unroll
      for (int f = 0; f < 4; ++f)
        st[g][f] = __builtin_amdgcn_mfma_f32_16x16x32_bf16(kf[f], qf[g], zf, 0, 0, 0);

    const bool fullc = (kc + 64 <= L);
#pragma unroll
    for (int g = 0; g < 2; ++g) {
      float p[4][4];
      if (fullc) {
#pragma unroll
        for (int f = 0; f < 4; ++f)
#pragma unroll
          for (int r = 0; r < 4; ++r) {
            p[f][r] = __builtin_amdgcn_exp2f(st[g][f][r]);  // v_exp_f32
            l_loc[g] += p[f][r];
          }
      } else {
#pragma unroll
        for (int f = 0; f < 4; ++f)
#pragma unroll
          for (int r = 0; r < 4; ++r) {
            int kr = kc + f * 16 + lq * 4 + r;
            float pv = (kr < L) ? __builtin_amdgcn_exp2f(st[g][f][r]) : 0.f;
            p[f][r] = pv;
            l_loc[g] += pv;
          }
      }
      // P^T through shared per-wave buffer (in-order wave LDS: safe across g)
#pragma unroll
      for (int f = 0; f < 4; ++f) {
        u2v w;
        w[0] = packbf(p[f][0], p[f][1]);
        w[1] = packbf(p[f][2], p[f][3]);
        *(u2v*)(ptg + lrow * 36 + 8 * f + 2 * lq) = w;
      }
#pragma unroll
      for (int b = 0; b < 2; ++b) {
        u4v pv = *(const u4v*)(ptg + lrow * 36 + 16 * b + 4 * lq);
        union { u4v u; bfrag bf; } pt; pt.u = pv;
#pragma unroll
        for (int dj = 0; dj < 2; ++dj)
          o[g][dj] = __builtin_amdgcn_mfma_f32_16x16x32_bf16(av[dj][b], pt.bf, o[g][dj], 0, 0, 0);
      }
    }
  }

  // row-sum l: per-lane partials; reduce across the 4 lane-quads
  float l_i[2];
#pragma unroll
  for (int g = 0; g < 2; ++g) {
    float rs = l_loc[g];
    rs += __shfl_xor(rs, 16);
    rs += __shfl_xor(rs, 32);
    l_i[g] = rs;
  }

  // ---- tail: invalid q rows -> x = (1/1024) * colsum(V) (exact vs reference) ----
  if (nvalid < 32) {
#pragma unroll
    for (int g = 0; g < 2; ++g) {
      bool inv = (g * 16 + lrow) >= nvalid;
      if (inv) {
        l_i[g] = 1024.f;
#pragma unroll
        for (int dj = 0; dj < 2; ++dj)
#pragma unroll
          for (int r = 0; r < 4; ++r) o[g][dj][r] = 0.f;
      }
    }
    bfrag ind[2];
#pragma unroll
    for (int g = 0; g < 2; ++g) {
      short iv = ((g * 16 + lrow) >= nvalid) ? (short)0x3F80 : (short)0;
#pragma unroll
      for (int j = 0; j < 8; ++j) ind[g][j] = iv;
    }
    const bool g0 = (nvalid < 16);
#pragma unroll 2
    for (int kc = 0; kc < 1024; kc += 64) {
#pragma unroll
      for (int dj = 0; dj < 2; ++dj)
#pragma unroll
        for (int b = 0; b < 2; ++b) {
          bfrag av = *(const bfrag*)(Vb + (size_t)(dj * 16 + lrow) * 1024 + kc + b * 32 + lq * 8);
          if (g0)
            o[0][dj] = __builtin_amdgcn_mfma_f32_16x16x32_bf16(av, ind[0], o[0][dj], 0, 0, 0);
          o[1][dj] = __builtin_amdgcn_mfma_f32_16x16x32_bf16(av, ind[1], o[1][dj], 0, 0, 0);
        }
    }
  }

  // write x into qx: lane holds qrow = g*16+lrow, d = dj*16 + 4*lq + r
#pragma unroll
  for (int g = 0; g < 2; ++g) {
    float rcp = 1.0f / l_i[g];
#pragma unroll
    for (int dj = 0; dj < 2; ++dj) {
      u2v w;
      w[0] = packbf(o[g][dj][0] * rcp, o[g][dj][1] * rcp);
      w[1] = packbf(o[g][dj][2] * rcp, o[g][dj][3] * rcp);
      short* dst = qx + (g * 16 + lrow) * 264 + h * 32 + dj * 16 + lq * 4;
      *(u2v*)dst = w;
    }
  }
  __syncthreads();

  // ---- phase 3: output projection; wave computes cols wid*32..+31 ----
  {
    const int n0 = h * 32;
    ffrag acc[2][2] = {};
#pragma unroll
    for (int k0 = 0; k0 < 256; k0 += 32) {
      bfrag a[2], b[2];
#pragma unroll
      for (int i = 0; i < 2; ++i)
        a[i] = *(const bfrag*)(qx + (i * 16 + lrow) * 264 + k0 + lq * 8);
#pragma unroll
      for (int j = 0; j < 2; ++j)
        b[j] = cvt8(Wo + (size_t)(n0 + j * 16 + lrow) * 256 + k0 + lq * 8);
#pragma unroll
      for (int i = 0; i < 2; ++i)
#pragma unroll
        for (int j = 0; j < 2; ++j)
          acc[i][j] = __builtin_amdgcn_mfma_f32_16x16x32_bf16(a[i], b[j], acc[i][j], 0, 0, 0);
    }
#pragma unroll
    for (int j = 0; j < 2; ++j) {
      int d = n0 + j * 16 + lrow;
      float bs = bo[d];
#pragma unroll
      for (int i = 0; i < 2; ++i)
#pragma unroll
        for (int r = 0; r < 4; ++r)
          out[((size_t)bt * 1024 + q0 + i * 16 + lq * 4 + r) * 256 + d] = acc[i][j][r] + bs;
    }
  }
}

extern "C" void kernel_launch(void* const* d_in, const int* in_sizes, int n_in,
                              void* d_out, int out_size, void* d_ws, size_t ws_size,
                              hipStream_t stream) {
  const float* query = (const float*)d_in[0];
  const float* key   = (const float*)d_in[1];
  const float* value = (const float*)d_in[2];
  const int*   mask  = (const int*)d_in[3];
  const float* Wq = (const float*)d_in[4];
  const float* bq = (const float*)d_in[5];
  const float* Wk = (const float*)d_in[6];
  const float* bk = (const float*)d_in[7];
  const float* Wv = (const float*)d_in[8];
  const float* bv = (const float*)d_in[9];
  const float* Wo = (const float*)d_in[10];
  const float* bo = (const float*)d_in[11];
  float* out = (float*)d_out;

  // workspace: K bf16 (8 MB) + Vt bf16 (8 MB) = 16,777,216 bytes exactly
  short* k_ws  = (short*)d_ws;
  short* vt_ws = k_ws + 4194304;

  proj_kv<<<dim3(512), 256, 0, stream>>>(key, Wk, bk, value, Wv, bv, k_ws, vt_ws);
  attn_fused<<<dim3(512), 512, 0, stream>>>(query, Wq, bq, Wo, bo,
                                            k_ws, vt_ws, mask, out);
}

// Round 10
// 218.067 us; speedup vs baseline: 1.3639x; 1.0218x over previous
//
#include <hip/hip_runtime.h>

#define EXPC 0.25505654442163f  // (1/sqrt(32)) * log2(e)

typedef __attribute__((ext_vector_type(8))) short bfrag;   // 8 bf16
typedef __attribute__((ext_vector_type(4))) float ffrag;   // 4 f32 acc
typedef __attribute__((ext_vector_type(8))) unsigned int u8v;
typedef __attribute__((ext_vector_type(4))) unsigned int u4v;
typedef __attribute__((ext_vector_type(2))) unsigned int u2v;

__device__ __forceinline__ short f2bf(float x) {
  union { float f; unsigned u; } v; v.f = x;
  return (short)((v.u + 0x8000u) >> 16);  // round-half-up
}

__device__ __forceinline__ unsigned int packbf(float a, float b) {
  return __builtin_amdgcn_perm(__float_as_uint(b) + 0x8000u,
                               __float_as_uint(a) + 0x8000u, 0x07060302u);
}

__device__ __forceinline__ bfrag cvtp(u8v x) {
  u4v r;
#pragma unroll
  for (int i = 0; i < 4; ++i)
    r[i] = __builtin_amdgcn_perm(x[2 * i + 1] + 0x8000u, x[2 * i] + 0x8000u, 0x07060302u);
  union { u4v u; bfrag b; } c; c.u = r; return c.b;
}
__device__ __forceinline__ bfrag cvt8(const float* __restrict__ p) {
  return cvtp(*(const u8v*)p);
}

// ---- fused K+V projection v2: split-d (1024 blocks, 4/CU) + pipelined staging ----
// blocks 0..511:   K: (row-tile 64) x (d-half 128) -> ko[16384][256]
// blocks 512..1023: V: (row-tile 64) x (d-half 128) -> vt[bt][256][1024] (transposed)
__global__ __launch_bounds__(256, 4) void proj_kv(
    const float* __restrict__ kin, const float* __restrict__ Wk,
    const float* __restrict__ bk, const float* __restrict__ vin,
    const float* __restrict__ Wv, const float* __restrict__ bv,
    short* __restrict__ ko, short* __restrict__ vt) {
  const int t = threadIdx.x;
  const int lane = t & 63, wid = t >> 6;
  const int lrow = lane & 15, lq = lane >> 4;
  __shared__ __align__(16) char lds[18432];
  const int row4 = t >> 2, c4 = (t & 3) * 8;

  const bool isK = blockIdx.x < 512;
  if (isK) {
    const int bx = blockIdx.x >> 1, d0 = (blockIdx.x & 1) * 128;
    const int m0 = bx * 64;
    short* Ab = (short*)lds;             // kin slab [64][40]
    short* Bb = (short*)(lds + 5120);    // Wk slab [128][40]
    short* tile = (short*)lds;
    ffrag acc[4][2] = {};
    u8v pa, pb0, pb1;
    pa  = *(const u8v*)(kin + (size_t)(m0 + row4) * 256 + c4);
    pb0 = *(const u8v*)(Wk + (size_t)(d0 + row4) * 256 + c4);
    pb1 = *(const u8v*)(Wk + (size_t)(d0 + 64 + row4) * 256 + c4);
    *(bfrag*)(Ab + row4 * 40 + c4) = cvtp(pa);
    *(bfrag*)(Bb + row4 * 40 + c4) = cvtp(pb0);
    *(bfrag*)(Bb + (64 + row4) * 40 + c4) = cvtp(pb1);
#pragma unroll 1
    for (int s = 0; s < 8; ++s) {
      __syncthreads();
      if (s < 7) {
        const int k1 = (s + 1) * 32;
        pa  = *(const u8v*)(kin + (size_t)(m0 + row4) * 256 + k1 + c4);
        pb0 = *(const u8v*)(Wk + (size_t)(d0 + row4) * 256 + k1 + c4);
        pb1 = *(const u8v*)(Wk + (size_t)(d0 + 64 + row4) * 256 + k1 + c4);
      }
      bfrag a[4], b[2];
#pragma unroll
      for (int i = 0; i < 4; ++i)
        a[i] = *(const bfrag*)(Ab + (i * 16 + lrow) * 40 + lq * 8);
#pragma unroll
      for (int j = 0; j < 2; ++j)
        b[j] = *(const bfrag*)(Bb + (wid * 32 + j * 16 + lrow) * 40 + lq * 8);
#pragma unroll
      for (int i = 0; i < 4; ++i)
#pragma unroll
        for (int j = 0; j < 2; ++j)
          acc[i][j] = __builtin_amdgcn_mfma_f32_16x16x32_bf16(a[i], b[j], acc[i][j], 0, 0, 0);
      __syncthreads();
      if (s < 7) {
        *(bfrag*)(Ab + row4 * 40 + c4) = cvtp(pa);
        *(bfrag*)(Bb + row4 * 40 + c4) = cvtp(pb0);
        *(bfrag*)(Bb + (64 + row4) * 40 + c4) = cvtp(pb1);
      }
    }
    __syncthreads();
#pragma unroll
    for (int j = 0; j < 2; ++j) {
      int dl = wid * 32 + j * 16 + lrow;
      float bs = bk[d0 + dl];
#pragma unroll
      for (int i = 0; i < 4; ++i)
#pragma unroll
        for (int r = 0; r < 4; ++r)
          tile[(i * 16 + lq * 4 + r) * 136 + dl] = f2bf(acc[i][j][r] + bs);
    }
    __syncthreads();
#pragma unroll
    for (int p = 0; p < 4; ++p) {
      int id2 = p * 256 + t;
      int row = id2 >> 4, c = id2 & 15;
      bfrag v = *(const bfrag*)(tile + row * 136 + c * 8);
      *(bfrag*)(ko + (size_t)(m0 + row) * 256 + d0 + c * 8) = v;
    }
  } else {
    const int t2 = blockIdx.x - 512;
    const int bx = t2 >> 1, d0 = (t2 & 1) * 128;
    const int n0 = bx * 64;  // vin rows
    short* Aw = (short*)lds;             // Wv slab [128][40]
    short* Bv = (short*)(lds + 10240);   // vin slab [64][40]
    short* tile = (short*)lds;
    ffrag acc[2][4] = {};
    u8v pv, pw0, pw1;
    pw0 = *(const u8v*)(Wv + (size_t)(d0 + row4) * 256 + c4);
    pw1 = *(const u8v*)(Wv + (size_t)(d0 + 64 + row4) * 256 + c4);
    pv  = *(const u8v*)(vin + (size_t)(n0 + row4) * 256 + c4);
    *(bfrag*)(Aw + row4 * 40 + c4) = cvtp(pw0);
    *(bfrag*)(Aw + (64 + row4) * 40 + c4) = cvtp(pw1);
    *(bfrag*)(Bv + row4 * 40 + c4) = cvtp(pv);
#pragma unroll 1
    for (int s = 0; s < 8; ++s) {
      __syncthreads();
      if (s < 7) {
        const int k1 = (s + 1) * 32;
        pw0 = *(const u8v*)(Wv + (size_t)(d0 + row4) * 256 + k1 + c4);
        pw1 = *(const u8v*)(Wv + (size_t)(d0 + 64 + row4) * 256 + k1 + c4);
        pv  = *(const u8v*)(vin + (size_t)(n0 + row4) * 256 + k1 + c4);
      }
      bfrag a[2], b[4];
#pragma unroll
      for (int i = 0; i < 2; ++i)
        a[i] = *(const bfrag*)(Aw + (wid * 32 + i * 16 + lrow) * 40 + lq * 8);
#pragma unroll
      for (int j = 0; j < 4; ++j)
        b[j] = *(const bfrag*)(Bv + (j * 16 + lrow) * 40 + lq * 8);
#pragma unroll
      for (int i = 0; i < 2; ++i)
#pragma unroll
        for (int j = 0; j < 4; ++j)
          acc[i][j] = __builtin_amdgcn_mfma_f32_16x16x32_bf16(a[i], b[j], acc[i][j], 0, 0, 0);
      __syncthreads();
      if (s < 7) {
        *(bfrag*)(Aw + row4 * 40 + c4) = cvtp(pw0);
        *(bfrag*)(Aw + (64 + row4) * 40 + c4) = cvtp(pw1);
        *(bfrag*)(Bv + row4 * 40 + c4) = cvtp(pv);
      }
    }
    __syncthreads();
#pragma unroll
    for (int i = 0; i < 2; ++i)
#pragma unroll
      for (int r = 0; r < 4; ++r) {
        int dl = wid * 32 + i * 16 + lq * 4 + r;
        float bs = bv[d0 + dl];
#pragma unroll
        for (int j = 0; j < 4; ++j)
          tile[dl * 72 + j * 16 + lrow] = f2bf(acc[i][j][r] + bs);
      }
    __syncthreads();
    const int bt = n0 >> 10, sl0 = n0 & 1023;
#pragma unroll
    for (int p = 0; p < 4; ++p) {
      int id2 = p * 256 + t;
      int dl = id2 >> 3, c = id2 & 7;
      bfrag v = *(const bfrag*)(tile + dl * 72 + c * 8);
      *(bfrag*)(vt + (size_t)bt * 262144 + (size_t)(d0 + dl) * 1024 + sl0 + c * 8) = v;
    }
  }
}

// ---- fused: Q-proj(pre-scaled) -> attention (S^T, kf-prefetch) -> out-proj ----
// grid 512 x 512 thr; 32 q-rows/block; 1 head/wave, 2 g-streams; shared per-wave P buf.
__global__ __launch_bounds__(512, 4) void attn_fused(
    const float* __restrict__ query, const float* __restrict__ Wq,
    const float* __restrict__ bq, const float* __restrict__ Wo,
    const float* __restrict__ bo, const short* __restrict__ K,
    const short* __restrict__ Vt, const int* __restrict__ mask,
    float* __restrict__ out) {
  const int lane = threadIdx.x & 63, wid = threadIdx.x >> 6;  // wid = head
  const int lrow = lane & 15, lq = lane >> 4;
  const int id = blockIdx.x;
  const int bt = (id + (id >> 8)) & 15;  // CU-pair (id, id+256) -> different L
  const int q0 = (id >> 4) * 32;
  const int L = mask[bt];
  const int h = wid;

  __shared__ __align__(16) short qx[32 * 264];              // 16.9 KB: Q tile -> X tile
  __shared__ __align__(16) unsigned int ptbuf[8][16 * 36];  // 18.4 KB: per-wave P^T
  unsigned int* ptg = &ptbuf[wid][0];

  // ---- phase 1: Q projection into LDS, pre-scaled by EXPC; next-slab prefetch ----
  {
    const int n0 = h * 32;
    const float* X = query + ((size_t)bt * 1024 + q0) * 256;
    ffrag acc[2][2] = {};
    u8v xa[2], wb[2], xa_n[2], wb_n[2];
#pragma unroll
    for (int i = 0; i < 2; ++i)
      xa[i] = *(const u8v*)(X + (size_t)(i * 16 + lrow) * 256 + lq * 8);
#pragma unroll
    for (int j = 0; j < 2; ++j)
      wb[j] = *(const u8v*)(Wq + (size_t)(n0 + j * 16 + lrow) * 256 + lq * 8);
#pragma unroll 1
    for (int tt = 0; tt < 8; ++tt) {
      if (tt < 7) {
        const int kk = (tt + 1) * 32;
#pragma unroll
        for (int i = 0; i < 2; ++i)
          xa_n[i] = *(const u8v*)(X + (size_t)(i * 16 + lrow) * 256 + kk + lq * 8);
#pragma unroll
        for (int j = 0; j < 2; ++j)
          wb_n[j] = *(const u8v*)(Wq + (size_t)(n0 + j * 16 + lrow) * 256 + kk + lq * 8);
      }
      bfrag a[2], b[2];
#pragma unroll
      for (int i = 0; i < 2; ++i) a[i] = cvtp(xa[i]);
#pragma unroll
      for (int j = 0; j < 2; ++j) b[j] = cvtp(wb[j]);
#pragma unroll
      for (int i = 0; i < 2; ++i)
#pragma unroll
        for (int j = 0; j < 2; ++j)
          acc[i][j] = __builtin_amdgcn_mfma_f32_16x16x32_bf16(a[i], b[j], acc[i][j], 0, 0, 0);
#pragma unroll
      for (int i = 0; i < 2; ++i) xa[i] = xa_n[i];
#pragma unroll
      for (int j = 0; j < 2; ++j) wb[j] = wb_n[j];
    }
#pragma unroll
    for (int j = 0; j < 2; ++j) {
      int d = n0 + j * 16 + lrow;
      float bs = bq[d];
#pragma unroll
      for (int i = 0; i < 2; ++i)
#pragma unroll
        for (int r = 0; r < 4; ++r)
          qx[(i * 16 + lq * 4 + r) * 264 + d] = f2bf((acc[i][j][r] + bs) * EXPC);
    }
  }
  // no barrier: wave reads only its own columns until phase 3

  // ---- phase 2: S^T = K·Q^T; kf prefetched one chunk ahead ----
  const short* Kb = K + (size_t)bt * 262144;            // [1024][256]
  const short* Vb = Vt + ((size_t)bt * 8 + h) * 32768;  // [32][1024]
  bfrag qf[2];
#pragma unroll
  for (int g = 0; g < 2; ++g)
    qf[g] = *(const bfrag*)(qx + (g * 16 + lrow) * 264 + h * 32 + lq * 8);

  const int nvalid = min(max(L - q0, 0), 32);
  const int nchunk = (nvalid > 0) ? ((L + 63) >> 6) : 0;

  float l_loc[2] = {0.f, 0.f};
  ffrag o[2][2] = {};  // o[g][dj]

  bfrag kf[4], kf_n[4];
  if (nchunk > 0) {
#pragma unroll
    for (int f = 0; f < 4; ++f)
      kf[f] = *(const bfrag*)(Kb + (size_t)(f * 16 + lrow) * 256 + h * 32 + lq * 8);
  }

#pragma unroll 1
  for (int c = 0; c < nchunk; ++c) {
    const int kc = c * 64;
    const ffrag zf = {0.f, 0.f, 0.f, 0.f};
    if (c + 1 < nchunk) {
#pragma unroll
      for (int f = 0; f < 4; ++f)
        kf_n[f] = *(const bfrag*)(Kb + (size_t)(kc + 64 + f * 16 + lrow) * 256 + h * 32 + lq * 8);
    }
    bfrag av[2][2];
#pragma unroll
    for (int dj = 0; dj < 2; ++dj)
#pragma unroll
      for (int b = 0; b < 2; ++b)
        av[dj][b] = *(const bfrag*)(Vb + (size_t)(dj * 16 + lrow) * 1024 + kc + b * 32 + lq * 8);

    ffrag st[2][4];
#pragma unroll
    for (int g = 0; g < 2; ++g)
#pragma unroll
      for (int f = 0; f < 4; ++f)
        st[g][f] = __builtin_amdgcn_mfma_f32_16x16x32_bf16(kf[f], qf[g], zf, 0, 0, 0);

    const bool fullc = (kc + 64 <= L);
#pragma unroll
    for (int g = 0; g < 2; ++g) {
      float p[4][4];
      if (fullc) {
#pragma unroll
        for (int f = 0; f < 4; ++f)
#pragma unroll
          for (int r = 0; r < 4; ++r) {
            p[f][r] = __builtin_amdgcn_exp2f(st[g][f][r]);
            l_loc[g] += p[f][r];
          }
      } else {
#pragma unroll
        for (int f = 0; f < 4; ++f)
#pragma unroll
          for (int r = 0; r < 4; ++r) {
            int kr = kc + f * 16 + lq * 4 + r;
            float pv = (kr < L) ? __builtin_amdgcn_exp2f(st[g][f][r]) : 0.f;
            p[f][r] = pv;
            l_loc[g] += pv;
          }
      }
#pragma unroll
      for (int f = 0; f < 4; ++f) {
        u2v w;
        w[0] = packbf(p[f][0], p[f][1]);
        w[1] = packbf(p[f][2], p[f][3]);
        *(u2v*)(ptg + lrow * 36 + 8 * f + 2 * lq) = w;
      }
#pragma unroll
      for (int b = 0; b < 2; ++b) {
        u4v pv = *(const u4v*)(ptg + lrow * 36 + 16 * b + 4 * lq);
        union { u4v u; bfrag bf; } pt; pt.u = pv;
#pragma unroll
        for (int dj = 0; dj < 2; ++dj)
          o[g][dj] = __builtin_amdgcn_mfma_f32_16x16x32_bf16(av[dj][b], pt.bf, o[g][dj], 0, 0, 0);
      }
    }
#pragma unroll
    for (int f = 0; f < 4; ++f) kf[f] = kf_n[f];
  }

  // row-sum l: per-lane partials; reduce across the 4 lane-quads
  float l_i[2];
#pragma unroll
  for (int g = 0; g < 2; ++g) {
    float rs = l_loc[g];
    rs += __shfl_xor(rs, 16);
    rs += __shfl_xor(rs, 32);
    l_i[g] = rs;
  }

  // ---- tail: invalid q rows -> x = (1/1024) * colsum(V) (exact vs reference) ----
  if (nvalid < 32) {
#pragma unroll
    for (int g = 0; g < 2; ++g) {
      bool inv = (g * 16 + lrow) >= nvalid;
      if (inv) {
        l_i[g] = 1024.f;
#pragma unroll
        for (int dj = 0; dj < 2; ++dj)
#pragma unroll
          for (int r = 0; r < 4; ++r) o[g][dj][r] = 0.f;
      }
    }
    bfrag ind[2];
#pragma unroll
    for (int g = 0; g < 2; ++g) {
      short iv = ((g * 16 + lrow) >= nvalid) ? (short)0x3F80 : (short)0;
#pragma unroll
      for (int j = 0; j < 8; ++j) ind[g][j] = iv;
    }
    const bool g0 = (nvalid < 16);
#pragma unroll 2
    for (int kc = 0; kc < 1024; kc += 64) {
#pragma unroll
      for (int dj = 0; dj < 2; ++dj)
#pragma unroll
        for (int b = 0; b < 2; ++b) {
          bfrag av = *(const bfrag*)(Vb + (size_t)(dj * 16 + lrow) * 1024 + kc + b * 32 + lq * 8);
          if (g0)
            o[0][dj] = __builtin_amdgcn_mfma_f32_16x16x32_bf16(av, ind[0], o[0][dj], 0, 0, 0);
          o[1][dj] = __builtin_amdgcn_mfma_f32_16x16x32_bf16(av, ind[1], o[1][dj], 0, 0, 0);
        }
    }
  }

  // write x into qx: lane holds qrow = g*16+lrow, d = dj*16 + 4*lq + r
#pragma unroll
  for (int g = 0; g < 2; ++g) {
    float rcp = 1.0f / l_i[g];
#pragma unroll
    for (int dj = 0; dj < 2; ++dj) {
      u2v w;
      w[0] = packbf(o[g][dj][0] * rcp, o[g][dj][1] * rcp);
      w[1] = packbf(o[g][dj][2] * rcp, o[g][dj][3] * rcp);
      short* dst = qx + (g * 16 + lrow) * 264 + h * 32 + dj * 16 + lq * 4;
      *(u2v*)dst = w;
    }
  }
  __syncthreads();

  // ---- phase 3: output projection; Wo prefetched one slab ahead ----
  {
    const int n0 = h * 32;
    ffrag acc[2][2] = {};
    u8v wb[2], wb_n[2];
#pragma unroll
    for (int j = 0; j < 2; ++j)
      wb[j] = *(const u8v*)(Wo + (size_t)(n0 + j * 16 + lrow) * 256 + lq * 8);
#pragma unroll 1
    for (int tt = 0; tt < 8; ++tt) {
      const int k0 = tt * 32;
      if (tt < 7) {
#pragma unroll
        for (int j = 0; j < 2; ++j)
          wb_n[j] = *(const u8v*)(Wo + (size_t)(n0 + j * 16 + lrow) * 256 + k0 + 32 + lq * 8);
      }
      bfrag a[2], b[2];
#pragma unroll
      for (int i = 0; i < 2; ++i)
        a[i] = *(const bfrag*)(qx + (i * 16 + lrow) * 264 + k0 + lq * 8);
#pragma unroll
      for (int j = 0; j < 2; ++j) b[j] = cvtp(wb[j]);
#pragma unroll
      for (int i = 0; i < 2; ++i)
#pragma unroll
        for (int j = 0; j < 2; ++j)
          acc[i][j] = __builtin_amdgcn_mfma_f32_16x16x32_bf16(a[i], b[j], acc[i][j], 0, 0, 0);
#pragma unroll
      for (int j = 0; j < 2; ++j) wb[j] = wb_n[j];
    }
#pragma unroll
    for (int j = 0; j < 2; ++j) {
      int d = n0 + j * 16 + lrow;
      float bs = bo[d];
#pragma unroll
      for (int i = 0; i < 2; ++i)
#pragma unroll
        for (int r = 0; r < 4; ++r)
          out[((size_t)bt * 1024 + q0 + i * 16 + lq * 4 + r) * 256 + d] = acc[i][j][r] + bs;
    }
  }
}

extern "C" void kernel_launch(void* const* d_in, const int* in_sizes, int n_in,
                              void* d_out, int out_size, void* d_ws, size_t ws_size,
                              hipStream_t stream) {
  const float* query = (const float*)d_in[0];
  const float* key   = (const float*)d_in[1];
  const float* value = (const float*)d_in[2];
  const int*   mask  = (const int*)d_in[3];
  const float* Wq = (const float*)d_in[4];
  const float* bq = (const float*)d_in[5];
  const float* Wk = (const float*)d_in[6];
  const float* bk = (const float*)d_in[7];
  const float* Wv = (const float*)d_in[8];
  const float* bv = (const float*)d_in[9];
  const float* Wo = (const float*)d_in[10];
  const float* bo = (const float*)d_in[11];
  float* out = (float*)d_out;

  // workspace: K bf16 (8 MB) + Vt bf16 (8 MB) = 16,777,216 bytes exactly
  short* k_ws  = (short*)d_ws;
  short* vt_ws = k_ws + 4194304;

  proj_kv<<<dim3(1024), 256, 0, stream>>>(key, Wk, bk, value, Wv, bv, k_ws, vt_ws);
  attn_fused<<<dim3(512), 512, 0, stream>>>(query, Wq, bq, Wo, bo,
                                            k_ws, vt_ws, mask, out);
}

// Round 11
// 204.284 us; speedup vs baseline: 1.4560x; 1.0675x over previous
//
#include <hip/hip_runtime.h>

#define EXPC 0.25505654442163f  // (1/sqrt(32)) * log2(e)

typedef __attribute__((ext_vector_type(8))) short bfrag;   // 8 bf16
typedef __attribute__((ext_vector_type(4))) float ffrag;   // 4 f32 acc
typedef __attribute__((ext_vector_type(8))) unsigned int u8v;
typedef __attribute__((ext_vector_type(4))) unsigned int u4v;
typedef __attribute__((ext_vector_type(2))) unsigned int u2v;

__device__ __forceinline__ short f2bf(float x) {
  union { float f; unsigned u; } v; v.f = x;
  return (short)((v.u + 0x8000u) >> 16);  // round-half-up
}

__device__ __forceinline__ unsigned int packbf(float a, float b) {
  return __builtin_amdgcn_perm(__float_as_uint(b) + 0x8000u,
                               __float_as_uint(a) + 0x8000u, 0x07060302u);
}

__device__ __forceinline__ bfrag cvtp(u8v x) {
  u4v r;
#pragma unroll
  for (int i = 0; i < 4; ++i)
    r[i] = __builtin_amdgcn_perm(x[2 * i + 1] + 0x8000u, x[2 * i] + 0x8000u, 0x07060302u);
  union { u4v u; bfrag b; } c; c.u = r; return c.b;
}
__device__ __forceinline__ bfrag cvt8(const float* __restrict__ p) {
  return cvtp(*(const u8v*)p);
}

// ---- fused K+V projection v2 (verbatim from R10) ----
__global__ __launch_bounds__(256, 4) void proj_kv(
    const float* __restrict__ kin, const float* __restrict__ Wk,
    const float* __restrict__ bk, const float* __restrict__ vin,
    const float* __restrict__ Wv, const float* __restrict__ bv,
    short* __restrict__ ko, short* __restrict__ vt) {
  const int t = threadIdx.x;
  const int lane = t & 63, wid = t >> 6;
  const int lrow = lane & 15, lq = lane >> 4;
  __shared__ __align__(16) char lds[18432];
  const int row4 = t >> 2, c4 = (t & 3) * 8;

  const bool isK = blockIdx.x < 512;
  if (isK) {
    const int bx = blockIdx.x >> 1, d0 = (blockIdx.x & 1) * 128;
    const int m0 = bx * 64;
    short* Ab = (short*)lds;
    short* Bb = (short*)(lds + 5120);
    short* tile = (short*)lds;
    ffrag acc[4][2] = {};
    u8v pa, pb0, pb1;
    pa  = *(const u8v*)(kin + (size_t)(m0 + row4) * 256 + c4);
    pb0 = *(const u8v*)(Wk + (size_t)(d0 + row4) * 256 + c4);
    pb1 = *(const u8v*)(Wk + (size_t)(d0 + 64 + row4) * 256 + c4);
    *(bfrag*)(Ab + row4 * 40 + c4) = cvtp(pa);
    *(bfrag*)(Bb + row4 * 40 + c4) = cvtp(pb0);
    *(bfrag*)(Bb + (64 + row4) * 40 + c4) = cvtp(pb1);
#pragma unroll 1
    for (int s = 0; s < 8; ++s) {
      __syncthreads();
      if (s < 7) {
        const int k1 = (s + 1) * 32;
        pa  = *(const u8v*)(kin + (size_t)(m0 + row4) * 256 + k1 + c4);
        pb0 = *(const u8v*)(Wk + (size_t)(d0 + row4) * 256 + k1 + c4);
        pb1 = *(const u8v*)(Wk + (size_t)(d0 + 64 + row4) * 256 + k1 + c4);
      }
      bfrag a[4], b[2];
#pragma unroll
      for (int i = 0; i < 4; ++i)
        a[i] = *(const bfrag*)(Ab + (i * 16 + lrow) * 40 + lq * 8);
#pragma unroll
      for (int j = 0; j < 2; ++j)
        b[j] = *(const bfrag*)(Bb + (wid * 32 + j * 16 + lrow) * 40 + lq * 8);
#pragma unroll
      for (int i = 0; i < 4; ++i)
#pragma unroll
        for (int j = 0; j < 2; ++j)
          acc[i][j] = __builtin_amdgcn_mfma_f32_16x16x32_bf16(a[i], b[j], acc[i][j], 0, 0, 0);
      __syncthreads();
      if (s < 7) {
        *(bfrag*)(Ab + row4 * 40 + c4) = cvtp(pa);
        *(bfrag*)(Bb + row4 * 40 + c4) = cvtp(pb0);
        *(bfrag*)(Bb + (64 + row4) * 40 + c4) = cvtp(pb1);
      }
    }
    __syncthreads();
#pragma unroll
    for (int j = 0; j < 2; ++j) {
      int dl = wid * 32 + j * 16 + lrow;
      float bs = bk[d0 + dl];
#pragma unroll
      for (int i = 0; i < 4; ++i)
#pragma unroll
        for (int r = 0; r < 4; ++r)
          tile[(i * 16 + lq * 4 + r) * 136 + dl] = f2bf(acc[i][j][r] + bs);
    }
    __syncthreads();
#pragma unroll
    for (int p = 0; p < 4; ++p) {
      int id2 = p * 256 + t;
      int row = id2 >> 4, c = id2 & 15;
      bfrag v = *(const bfrag*)(tile + row * 136 + c * 8);
      *(bfrag*)(ko + (size_t)(m0 + row) * 256 + d0 + c * 8) = v;
    }
  } else {
    const int t2 = blockIdx.x - 512;
    const int bx = t2 >> 1, d0 = (t2 & 1) * 128;
    const int n0 = bx * 64;
    short* Aw = (short*)lds;
    short* Bv = (short*)(lds + 10240);
    short* tile = (short*)lds;
    ffrag acc[2][4] = {};
    u8v pv, pw0, pw1;
    pw0 = *(const u8v*)(Wv + (size_t)(d0 + row4) * 256 + c4);
    pw1 = *(const u8v*)(Wv + (size_t)(d0 + 64 + row4) * 256 + c4);
    pv  = *(const u8v*)(vin + (size_t)(n0 + row4) * 256 + c4);
    *(bfrag*)(Aw + row4 * 40 + c4) = cvtp(pw0);
    *(bfrag*)(Aw + (64 + row4) * 40 + c4) = cvtp(pw1);
    *(bfrag*)(Bv + row4 * 40 + c4) = cvtp(pv);
#pragma unroll 1
    for (int s = 0; s < 8; ++s) {
      __syncthreads();
      if (s < 7) {
        const int k1 = (s + 1) * 32;
        pw0 = *(const u8v*)(Wv + (size_t)(d0 + row4) * 256 + k1 + c4);
        pw1 = *(const u8v*)(Wv + (size_t)(d0 + 64 + row4) * 256 + k1 + c4);
        pv  = *(const u8v*)(vin + (size_t)(n0 + row4) * 256 + k1 + c4);
      }
      bfrag a[2], b[4];
#pragma unroll
      for (int i = 0; i < 2; ++i)
        a[i] = *(const bfrag*)(Aw + (wid * 32 + i * 16 + lrow) * 40 + lq * 8);
#pragma unroll
      for (int j = 0; j < 4; ++j)
        b[j] = *(const bfrag*)(Bv + (j * 16 + lrow) * 40 + lq * 8);
#pragma unroll
      for (int i = 0; i < 2; ++i)
#pragma unroll
        for (int j = 0; j < 4; ++j)
          acc[i][j] = __builtin_amdgcn_mfma_f32_16x16x32_bf16(a[i], b[j], acc[i][j], 0, 0, 0);
      __syncthreads();
      if (s < 7) {
        *(bfrag*)(Aw + row4 * 40 + c4) = cvtp(pw0);
        *(bfrag*)(Aw + (64 + row4) * 40 + c4) = cvtp(pw1);
        *(bfrag*)(Bv + row4 * 40 + c4) = cvtp(pv);
      }
    }
    __syncthreads();
#pragma unroll
    for (int i = 0; i < 2; ++i)
#pragma unroll
      for (int r = 0; r < 4; ++r) {
        int dl = wid * 32 + i * 16 + lq * 4 + r;
        float bs = bv[d0 + dl];
#pragma unroll
        for (int j = 0; j < 4; ++j)
          tile[dl * 72 + j * 16 + lrow] = f2bf(acc[i][j][r] + bs);
      }
    __syncthreads();
    const int bt = n0 >> 10, sl0 = n0 & 1023;
#pragma unroll
    for (int p = 0; p < 4; ++p) {
      int id2 = p * 256 + t;
      int dl = id2 >> 3, c = id2 & 7;
      bfrag v = *(const bfrag*)(tile + dl * 72 + c * 8);
      *(bfrag*)(vt + (size_t)bt * 262144 + (size_t)(d0 + dl) * 1024 + sl0 + c * 8) = v;
    }
  }
}

// ---- fused attn v3: early-exit invalid tiles; qt=31 computes+broadcasts pad rows ----
// grid 512 x 512 thr; 32 q-rows/block; 1 head/wave, 2 g-streams.
__global__ __launch_bounds__(512, 4) void attn_fused(
    const float* __restrict__ query, const float* __restrict__ Wq,
    const float* __restrict__ bq, const float* __restrict__ Wo,
    const float* __restrict__ bo, const short* __restrict__ K,
    const short* __restrict__ Vt, const int* __restrict__ mask,
    float* __restrict__ out) {
  const int lane = threadIdx.x & 63, wid = threadIdx.x >> 6;  // wid = head
  const int lrow = lane & 15, lq = lane >> 4;
  const int id = blockIdx.x;
  const int bt = (id + (id >> 8)) & 15;  // CU-pair gets different L
  const int qt = id >> 4;
  const int q0 = qt * 32;
  const int L = mask[bt];
  const int h = wid;
  const bool isLast = (qt == 31);
  const int nvalid = min(max(L - q0, 0), 32);

  if (nvalid <= 0 && !isLast) return;  // rows covered by qt=31 broadcast
  const bool colsumOnly = isLast && (nvalid <= 0);

  __shared__ __align__(16) short qx[32 * 264];              // Q tile -> X tile
  __shared__ __align__(16) unsigned int ptbuf[8][16 * 36];  // per-wave P^T
  unsigned int* ptg = &ptbuf[wid][0];
  float* vbuf = (float*)&ptbuf[0][0];                       // broadcast vector (D-mode)

  const short* Vb = Vt + ((size_t)bt * 8 + h) * 32768;  // [32][1024]
  float l_i[2];
  ffrag o[2][2] = {};  // o[g][dj]

  if (!colsumOnly) {
    // ---- phase 1: Q projection into LDS, pre-scaled by EXPC; slab prefetch ----
    {
      const int n0 = h * 32;
      const float* X = query + ((size_t)bt * 1024 + q0) * 256;
      ffrag acc[2][2] = {};
      u8v xa[2], wb[2], xa_n[2], wb_n[2];
#pragma unroll
      for (int i = 0; i < 2; ++i)
        xa[i] = *(const u8v*)(X + (size_t)(i * 16 + lrow) * 256 + lq * 8);
#pragma unroll
      for (int j = 0; j < 2; ++j)
        wb[j] = *(const u8v*)(Wq + (size_t)(n0 + j * 16 + lrow) * 256 + lq * 8);
#pragma unroll 1
      for (int tt = 0; tt < 8; ++tt) {
        if (tt < 7) {
          const int kk = (tt + 1) * 32;
#pragma unroll
          for (int i = 0; i < 2; ++i)
            xa_n[i] = *(const u8v*)(X + (size_t)(i * 16 + lrow) * 256 + kk + lq * 8);
#pragma unroll
          for (int j = 0; j < 2; ++j)
            wb_n[j] = *(const u8v*)(Wq + (size_t)(n0 + j * 16 + lrow) * 256 + kk + lq * 8);
        }
        bfrag a[2], b[2];
#pragma unroll
        for (int i = 0; i < 2; ++i) a[i] = cvtp(xa[i]);
#pragma unroll
        for (int j = 0; j < 2; ++j) b[j] = cvtp(wb[j]);
#pragma unroll
        for (int i = 0; i < 2; ++i)
#pragma unroll
          for (int j = 0; j < 2; ++j)
            acc[i][j] = __builtin_amdgcn_mfma_f32_16x16x32_bf16(a[i], b[j], acc[i][j], 0, 0, 0);
#pragma unroll
        for (int i = 0; i < 2; ++i) xa[i] = xa_n[i];
#pragma unroll
        for (int j = 0; j < 2; ++j) wb[j] = wb_n[j];
      }
#pragma unroll
      for (int j = 0; j < 2; ++j) {
        int d = n0 + j * 16 + lrow;
        float bs = bq[d];
#pragma unroll
        for (int i = 0; i < 2; ++i)
#pragma unroll
          for (int r = 0; r < 4; ++r)
            qx[(i * 16 + lq * 4 + r) * 264 + d] = f2bf((acc[i][j][r] + bs) * EXPC);
      }
    }
    // no barrier: wave reads only its own columns until phase 3

    // ---- phase 2: S^T = K·Q^T; kf prefetched one chunk ahead ----
    const short* Kb = K + (size_t)bt * 262144;  // [1024][256]
    bfrag qf[2];
#pragma unroll
    for (int g = 0; g < 2; ++g)
      qf[g] = *(const bfrag*)(qx + (g * 16 + lrow) * 264 + h * 32 + lq * 8);

    const int nchunk = (L + 63) >> 6;
    float l_loc[2] = {0.f, 0.f};
    bfrag kf[4], kf_n[4];
#pragma unroll
    for (int f = 0; f < 4; ++f)
      kf[f] = *(const bfrag*)(Kb + (size_t)(f * 16 + lrow) * 256 + h * 32 + lq * 8);

#pragma unroll 1
    for (int c = 0; c < nchunk; ++c) {
      const int kc = c * 64;
      const ffrag zf = {0.f, 0.f, 0.f, 0.f};
      if (c + 1 < nchunk) {
#pragma unroll
        for (int f = 0; f < 4; ++f)
          kf_n[f] = *(const bfrag*)(Kb + (size_t)(kc + 64 + f * 16 + lrow) * 256 + h * 32 + lq * 8);
      }
      bfrag av[2][2];
#pragma unroll
      for (int dj = 0; dj < 2; ++dj)
#pragma unroll
        for (int b = 0; b < 2; ++b)
          av[dj][b] = *(const bfrag*)(Vb + (size_t)(dj * 16 + lrow) * 1024 + kc + b * 32 + lq * 8);

      ffrag st[2][4];
#pragma unroll
      for (int g = 0; g < 2; ++g)
#pragma unroll
        for (int f = 0; f < 4; ++f)
          st[g][f] = __builtin_amdgcn_mfma_f32_16x16x32_bf16(kf[f], qf[g], zf, 0, 0, 0);

      const bool fullc = (kc + 64 <= L);
#pragma unroll
      for (int g = 0; g < 2; ++g) {
        float p[4][4];
        if (fullc) {
#pragma unroll
          for (int f = 0; f < 4; ++f)
#pragma unroll
            for (int r = 0; r < 4; ++r) {
              p[f][r] = __builtin_amdgcn_exp2f(st[g][f][r]);
              l_loc[g] += p[f][r];
            }
        } else {
#pragma unroll
          for (int f = 0; f < 4; ++f)
#pragma unroll
            for (int r = 0; r < 4; ++r) {
              int kr = kc + f * 16 + lq * 4 + r;
              float pv = (kr < L) ? __builtin_amdgcn_exp2f(st[g][f][r]) : 0.f;
              p[f][r] = pv;
              l_loc[g] += pv;
            }
        }
#pragma unroll
        for (int f = 0; f < 4; ++f) {
          u2v w;
          w[0] = packbf(p[f][0], p[f][1]);
          w[1] = packbf(p[f][2], p[f][3]);
          *(u2v*)(ptg + lrow * 36 + 8 * f + 2 * lq) = w;
        }
#pragma unroll
        for (int b = 0; b < 2; ++b) {
          u4v pv = *(const u4v*)(ptg + lrow * 36 + 16 * b + 4 * lq);
          union { u4v u; bfrag bf; } pt; pt.u = pv;
#pragma unroll
          for (int dj = 0; dj < 2; ++dj)
            o[g][dj] = __builtin_amdgcn_mfma_f32_16x16x32_bf16(av[dj][b], pt.bf, o[g][dj], 0, 0, 0);
        }
      }
#pragma unroll
      for (int f = 0; f < 4; ++f) kf[f] = kf_n[f];
    }

    // row-sum l across the 4 lane-quads
#pragma unroll
    for (int g = 0; g < 2; ++g) {
      float rs = l_loc[g];
      rs += __shfl_xor(rs, 16);
      rs += __shfl_xor(rs, 32);
      l_i[g] = rs;
    }
  } else {
#pragma unroll
    for (int g = 0; g < 2; ++g) l_i[g] = 1024.f;
  }

  // ---- tail (ONLY block qt=31): invalid rows -> colsum(V) via indicator MFMA ----
  if (isLast && nvalid < 32) {
#pragma unroll
    for (int g = 0; g < 2; ++g) {
      bool inv = (g * 16 + lrow) >= nvalid;
      if (inv) {
        l_i[g] = 1024.f;
#pragma unroll
        for (int dj = 0; dj < 2; ++dj)
#pragma unroll
          for (int r = 0; r < 4; ++r) o[g][dj][r] = 0.f;
      }
    }
    bfrag ind[2];
#pragma unroll
    for (int g = 0; g < 2; ++g) {
      short iv = ((g * 16 + lrow) >= nvalid) ? (short)0x3F80 : (short)0;
#pragma unroll
      for (int j = 0; j < 8; ++j) ind[g][j] = iv;
    }
    const bool g0 = (nvalid < 16);
#pragma unroll 2
    for (int kc = 0; kc < 1024; kc += 64) {
#pragma unroll
      for (int dj = 0; dj < 2; ++dj)
#pragma unroll
        for (int b = 0; b < 2; ++b) {
          bfrag av = *(const bfrag*)(Vb + (size_t)(dj * 16 + lrow) * 1024 + kc + b * 32 + lq * 8);
          if (g0)
            o[0][dj] = __builtin_amdgcn_mfma_f32_16x16x32_bf16(av, ind[0], o[0][dj], 0, 0, 0);
          o[1][dj] = __builtin_amdgcn_mfma_f32_16x16x32_bf16(av, ind[1], o[1][dj], 0, 0, 0);
        }
    }
  }

  // write x into qx: lane holds qrow = g*16+lrow, d = dj*16 + 4*lq + r
#pragma unroll
  for (int g = 0; g < 2; ++g) {
    float rcp = 1.0f / l_i[g];
#pragma unroll
    for (int dj = 0; dj < 2; ++dj) {
      u2v w;
      w[0] = packbf(o[g][dj][0] * rcp, o[g][dj][1] * rcp);
      w[1] = packbf(o[g][dj][2] * rcp, o[g][dj][3] * rcp);
      short* dst = qx + (g * 16 + lrow) * 264 + h * 32 + dj * 16 + lq * 4;
      *(u2v*)dst = w;
    }
  }
  __syncthreads();

  // ---- phase 3: output projection; Wo prefetched one slab ahead ----
  {
    const int n0 = h * 32;
    ffrag acc[2][2] = {};
    u8v wb[2], wb_n[2];
#pragma unroll
    for (int j = 0; j < 2; ++j)
      wb[j] = *(const u8v*)(Wo + (size_t)(n0 + j * 16 + lrow) * 256 + lq * 8);
#pragma unroll 1
    for (int tt = 0; tt < 8; ++tt) {
      const int k0 = tt * 32;
      if (tt < 7) {
#pragma unroll
        for (int j = 0; j < 2; ++j)
          wb_n[j] = *(const u8v*)(Wo + (size_t)(n0 + j * 16 + lrow) * 256 + k0 + 32 + lq * 8);
      }
      bfrag a[2], b[2];
#pragma unroll
      for (int i = 0; i < 2; ++i)
        a[i] = *(const bfrag*)(qx + (i * 16 + lrow) * 264 + k0 + lq * 8);
#pragma unroll
      for (int j = 0; j < 2; ++j) b[j] = cvtp(wb[j]);
#pragma unroll
      for (int i = 0; i < 2; ++i)
#pragma unroll
        for (int j = 0; j < 2; ++j)
          acc[i][j] = __builtin_amdgcn_mfma_f32_16x16x32_bf16(a[i], b[j], acc[i][j], 0, 0, 0);
#pragma unroll
      for (int j = 0; j < 2; ++j) wb[j] = wb_n[j];
    }

    if (!colsumOnly) {
      // normal store; partial blocks store only rows < L (block 31 stores all)
#pragma unroll
      for (int j = 0; j < 2; ++j) {
        int d = n0 + j * 16 + lrow;
        float bs = bo[d];
#pragma unroll
        for (int i = 0; i < 2; ++i)
#pragma unroll
          for (int r = 0; r < 4; ++r) {
            int qr = q0 + i * 16 + lq * 4 + r;
            if (qr < L || isLast)
              out[((size_t)bt * 1024 + qr) * 256 + d] = acc[i][j][r] + bs;
          }
      }
    } else {
      // D-mode: all rows identical -> build 256-vector in LDS, broadcast rows L..1023
      if (lq == 0) {
#pragma unroll
        for (int j = 0; j < 2; ++j) {
          int d = n0 + j * 16 + lrow;
          vbuf[d] = acc[0][j][0] + bo[d];
        }
      }
      __syncthreads();
      const int d = threadIdx.x & 255;
      const float vv = vbuf[d];
      float* ob = out + (size_t)bt * 1024 * 256 + d;
#pragma unroll 1
      for (int row = L + (threadIdx.x >> 8); row < 1024; row += 2)
        ob[(size_t)row * 256] = vv;
    }
  }
}

extern "C" void kernel_launch(void* const* d_in, const int* in_sizes, int n_in,
                              void* d_out, int out_size, void* d_ws, size_t ws_size,
                              hipStream_t stream) {
  const float* query = (const float*)d_in[0];
  const float* key   = (const float*)d_in[1];
  const float* value = (const float*)d_in[2];
  const int*   mask  = (const int*)d_in[3];
  const float* Wq = (const float*)d_in[4];
  const float* bq = (const float*)d_in[5];
  const float* Wk = (const float*)d_in[6];
  const float* bk = (const float*)d_in[7];
  const float* Wv = (const float*)d_in[8];
  const float* bv = (const float*)d_in[9];
  const float* Wo = (const float*)d_in[10];
  const float* bo = (const float*)d_in[11];
  float* out = (float*)d_out;

  // workspace: K bf16 (8 MB) + Vt bf16 (8 MB) = 16,777,216 bytes exactly
  short* k_ws  = (short*)d_ws;
  short* vt_ws = k_ws + 4194304;

  proj_kv<<<dim3(1024), 256, 0, stream>>>(key, Wk, bk, value, Wv, bv, k_ws, vt_ws);
  attn_fused<<<dim3(512), 512, 0, stream>>>(query, Wq, bq, Wo, bo,
                                            k_ws, vt_ws, mask, out);
}